// Round 16
// baseline (310.043 us; speedup 1.0000x reference)
//
#include <hip/hip_runtime.h>
#include <stdint.h>
#include <math.h>

static constexpr int B_   = 4;
static constexpr int N1   = 255780;   // total anchors per image across 5 levels
static constexpr int PRE  = 6000;
static constexpr int PREP = 6016;     // padded rows (multiple of 64)
static constexpr int POST = 1000;
static constexpr int MWORDS = 94;     // ceil(6000/64)
static constexpr int JMAX = 40;       // precomputed mask columns (stop measured ~24)
static constexpr int NCAND = 8192;    // candidate capacity per image
static constexpr int NBINS = 512;     // histogram bins
static constexpr int HGRP = 64;       // histogram partial groups per image
static constexpr int CNTSTRIDE = 32;  // ints; 128B — one cache line per image
static constexpr float NEGF = -1000000000.0f;

__device__ __constant__ int c_OFF[6] = {0,192000,240000,252000,255000,255780};
__device__ __constant__ int c_H[5]   = {200,100,50,25,13};
__device__ __constant__ int c_W[5]   = {320,160,80,40,20};
__device__ __constant__ int c_S[5]   = {4,8,16,32,64};

struct Ptrs { const float* cls[5]; const float* bbox[5]; };

// ---------- helpers ----------
__device__ __forceinline__ unsigned forder(float f) {
  unsigned u = __float_as_uint(f);
  return (u & 0x80000000u) ? ~u : (u | 0x80000000u);
}
__device__ __forceinline__ float funorder(unsigned u) {
  u = (u & 0x80000000u) ? (u & 0x7FFFFFFFu) : ~u;
  return __uint_as_float(u);
}
__device__ __forceinline__ int bucket_of(float s) {
  int bk = (int)(s * (float)NBINS);
  return max(0, min(NBINS - 1, bk));
}

// Exact division-free IoU test:  rn(inter/uni) > 0.7f  ⟺  inter ≥ m·uni,
// m = 0.7f + 2^-25 (midpoint to the next float; 0.7f mantissa is odd so the
// tie rounds UP). m(25b)×uni(24b) ≤ 49 bits → double product exact. uni > 0.
__device__ __forceinline__ bool iou_gt(float x1, float y1, float x2, float y2, float ai,
                                       float bx1, float by1, float bx2, float by2, float aj) {
  float xx1 = fmaxf(x1, bx1), yy1 = fmaxf(y1, by1);
  float xx2 = fminf(x2, bx2), yy2 = fminf(y2, by2);
  float ww = fmaxf(__fadd_rn(__fsub_rn(xx2, xx1), 1.0f), 0.0f);
  float hh = fmaxf(__fadd_rn(__fsub_rn(yy2, yy1), 1.0f), 0.0f);
  float inter = __fmul_rn(ww, hh);
  float uni = __fsub_rn(__fadd_rn(ai, aj), inter);
  return (double)inter >= ((double)0.7f + 0x1p-25) * (double)uni;
}
__device__ __forceinline__ float area_of(float ax1, float ay1, float ax2, float ay2) {
  return __fmul_rn(__fadd_rn(__fsub_rn(ax2, ax1), 1.0f),
                   __fadd_rn(__fsub_rn(ay2, ay1), 1.0f));
}

// score gather (no decode needed: with MIN_SIZE=0 every box is provably valid)
__device__ __forceinline__ float score_of(const Ptrs& P, int b, int i) {
  int lvl = (i >= c_OFF[4]) ? 4 : (i >= c_OFF[3]) ? 3 : (i >= c_OFF[2]) ? 2 : (i >= c_OFF[1]) ? 1 : 0;
  int rem = i - c_OFF[lvl];
  int a = rem % 3;
  int pos = rem / 3;
  size_t hw = (size_t)c_H[lvl] * c_W[lvl];
  return P.cls[lvl][((size_t)b * 6 + 3 + a) * hw + (size_t)pos];
}

// base anchor (legacy +1 convention), double math == numpy float64, rint == np.round
__device__ __forceinline__ void anchor_for(int lvl, int a, float& ax1, float& ay1, float& ax2, float& ay2) {
  int st = c_S[lvl];
  double size = (double)st * (double)st;
  double c = 0.5 * (double)(st - 1);
  double r = (a == 0) ? 0.5 : (a == 1) ? 1.0 : 2.0;
  double ws = rint(sqrt(size / r));
  double hs = rint(ws * r);
  double w2 = ws * 8.0, h2 = hs * 8.0;
  ax1 = (float)(c - 0.5 * (w2 - 1.0));
  ay1 = (float)(c - 0.5 * (h2 - 1.0));
  ax2 = (float)(c + 0.5 * (w2 - 1.0));
  ay2 = (float)(c + 0.5 * (h2 - 1.0));
}

// decode one anchor exactly as the reference (per-op f32 rounding, no FMA)
__device__ __forceinline__ void decode_one(const Ptrs& P, int b, int gi, float wlim, float hlim,
                                           float& x1, float& y1, float& x2, float& y2) {
  int lvl = (gi >= c_OFF[4]) ? 4 : (gi >= c_OFF[3]) ? 3 : (gi >= c_OFF[2]) ? 2 : (gi >= c_OFF[1]) ? 1 : 0;
  int rem = gi - c_OFF[lvl];
  int a = rem % 3;
  int pos = rem / 3;
  int W = c_W[lvl];
  int h = pos / W, w = pos - h * W;
  size_t hw = (size_t)c_H[lvl] * W;
  const float* bb = P.bbox[lvl] + ((size_t)b * 12 + 4 * a) * hw + (size_t)h * W + w;
  float d0 = bb[0], d1 = bb[hw], d2 = bb[2 * hw], d3 = bb[3 * hw];

  float ax1, ay1, ax2, ay2;
  anchor_for(lvl, a, ax1, ay1, ax2, ay2);
  int st = c_S[lvl];
  float sx = (float)(w * st), sy = (float)(h * st);
  ax1 += sx; ax2 += sx; ay1 += sy; ay2 += sy;   // exact integers

  float aw  = __fadd_rn(__fsub_rn(ax2, ax1), 1.0f);
  float ah  = __fadd_rn(__fsub_rn(ay2, ay1), 1.0f);
  float acx = __fadd_rn(ax1, __fmul_rn(0.5f, __fsub_rn(aw, 1.0f)));
  float acy = __fadd_rn(ay1, __fmul_rn(0.5f, __fsub_rn(ah, 1.0f)));
  float ew  = (float)exp((double)d2);
  float eh  = (float)exp((double)d3);
  float pcx = __fadd_rn(__fmul_rn(d0, aw), acx);
  float pcy = __fadd_rn(__fmul_rn(d1, ah), acy);
  float pw  = __fmul_rn(ew, aw);
  float ph  = __fmul_rn(eh, ah);
  float hwf = __fmul_rn(0.5f, __fsub_rn(pw, 1.0f));
  float hhf = __fmul_rn(0.5f, __fsub_rn(ph, 1.0f));
  x1 = __fsub_rn(pcx, hwf);
  x2 = __fadd_rn(pcx, hwf);
  y1 = __fsub_rn(pcy, hhf);
  y2 = __fadd_rn(pcy, hhf);
  x1 = fminf(fmaxf(x1, 0.0f), wlim);
  x2 = fminf(fmaxf(x2, 0.0f), wlim);
  y1 = fminf(fmaxf(y1, 0.0f), hlim);
  y2 = fminf(fmaxf(y2, 0.0f), hlim);
}

// ---------- kernel A: per-group partial histograms (no init, no global atomics) ----------
__global__ __launch_bounds__(1024) void k_hist(Ptrs P, int* hist) {
  const int b = blockIdx.y, g = blockIdx.x;    // HGRP groups per image
  __shared__ int h[NBINS];
  for (int k = threadIdx.x; k < NBINS; k += 1024) h[k] = 0;
  __syncthreads();
  const int step = HGRP * 1024;
  for (int i = g * 1024 + threadIdx.x; i < N1; i += step)
    atomicAdd(&h[bucket_of(score_of(P, b, i))], 1);
  __syncthreads();
  for (int k = threadIdx.x; k < NBINS; k += 1024)
    hist[((size_t)b * HGRP + g) * NBINS + k] = h[k];
}

// ---------- kernel B1: cutoff bin per image (sum partials + suffix-sum); zeroes cnt ----------
__global__ __launch_bounds__(NBINS) void k_cut(const int* hist, int* cutM, int* cnt) {
  int b = blockIdx.x, t = threadIdx.x;
  __shared__ int ts[NBINS];
  int mine = 0;
  for (int g = 0; g < HGRP; ++g) mine += hist[((size_t)b * HGRP + g) * NBINS + t];
  ts[t] = mine;
  if (t == 0) cnt[b * CNTSTRIDE] = 0;          // zero compaction counter (pre-k_compact)
  __syncthreads();
  for (int off = 1; off < NBINS; off <<= 1) {
    int v = ts[t] + ((t + off < NBINS) ? ts[t + off] : 0);
    __syncthreads();
    ts[t] = v;
    __syncthreads();
  }
  int nxt = (t + 1 < NBINS) ? ts[t + 1] : 0;
  if (ts[t] >= PRE && nxt < PRE) { cutM[b * 2] = t; cutM[b * 2 + 1] = ts[t]; }
}

// ---------- kernel B2: compact candidate keys — block-aggregated atomics ----------
__global__ __launch_bounds__(256) void k_compact(Ptrs P, const int* __restrict__ cutM, int* cnt,
                                                 unsigned long long* __restrict__ cand) {
  const int i = blockIdx.x * blockDim.x + threadIdx.x;
  const int b = blockIdx.y;
  const int wid = threadIdx.x >> 6;
  __shared__ int wcnts[4], wbase[4];

  int cut = cutM[b * 2];
  bool isc = false;
  float s = 0.0f;
  if (i < N1) {
    s = score_of(P, b, i);
    isc = bucket_of(s) >= cut;
  }
  unsigned long long ball = __ballot(isc);
  if ((threadIdx.x & 63) == 0) wcnts[wid] = __popcll(ball);
  __syncthreads();
  if (threadIdx.x == 0) {
    int tot = wcnts[0] + wcnts[1] + wcnts[2] + wcnts[3];
    int base = tot ? atomicAdd(&cnt[b * CNTSTRIDE], tot) : 0;
    wbase[0] = base;
    wbase[1] = base + wcnts[0];
    wbase[2] = base + wcnts[0] + wcnts[1];
    wbase[3] = base + wcnts[0] + wcnts[1] + wcnts[2];
  }
  __syncthreads();
  if (isc) {
    unsigned long long lower = ball & ((1ull << (threadIdx.x & 63)) - 1ull);
    int p = wbase[wid] + __popcll(lower);
    if (p < NCAND)
      cand[(size_t)b * NCAND + p] = ((unsigned long long)forder(s) << 32) |
                                    (unsigned long long)(0xFFFFFFFFu - (unsigned)i);
  }
}

// ---------- kernel B3a: full ranks per sc block (loop over jc; direct write) ----------
// Masked tile loads (slot<M ? key : 0) make stale cand slots inert: 0-keys
// never exceed a real key (real keys have the MSB set). Slots >= M get a
// garbage rank written but are never read (k_rankdec guards slot < M).
__global__ __launch_bounds__(1024) void k_rankp(const unsigned long long* __restrict__ cand,
                                                const int* __restrict__ cutM,
                                                int* __restrict__ rankA) {
  const int b = blockIdx.y, sc = blockIdx.x;   // 8 sc blocks
  const int M = min(cutM[b * 2 + 1], NCAND);
  if (sc * 1024 >= M) return;
  const int slot = sc * 1024 + threadIdx.x;
  __shared__ __align__(16) unsigned long long tile[1024];
  const unsigned long long* src = cand + (size_t)b * NCAND;
  unsigned long long my = (slot < M) ? src[slot] : ~0ull;
  int r = 0;
  const int njc = (M + 1023) >> 10;
  for (int jc = 0; jc < njc; ++jc) {
    __syncthreads();
    int ji = jc * 1024 + threadIdx.x;
    tile[threadIdx.x] = (ji < M) ? src[ji] : 0ull;
    __syncthreads();
    const ulonglong2* t2 = (const ulonglong2*)tile;
    #pragma unroll 8
    for (int t = 0; t < 512; ++t) { ulonglong2 v = t2[t]; r += (v.x > my) + (v.y > my); }
  }
  rankA[b * NCAND + slot] = r;
}

// ---------- kernel B3b+C fused: scatter by rank + decode boxes ----------
__global__ void k_rankdec(Ptrs P, const float* im_info,
                          const unsigned long long* cand, const int* rankA,
                          const int* cutM, float* selScore, float* boxes) {
  int b = blockIdx.y, slot = blockIdx.x * 256 + threadIdx.x;
  if (slot >= min(cutM[b * 2 + 1], NCAND)) return;   // stale slots: never ranked < PRE
  unsigned long long my = cand[(size_t)b * NCAND + slot];
  int r = rankA[b * NCAND + slot];
  if (r < PRE) {
    int gi = (int)(0xFFFFFFFFu - (unsigned)(my & 0xFFFFFFFFull));
    selScore[(size_t)b * PRE + r] = funorder((unsigned)(my >> 32));
    float wlim = __fsub_rn(im_info[b * 3 + 1], 1.0f);
    float hlim = __fsub_rn(im_info[b * 3 + 0], 1.0f);
    float x1, y1, x2, y2;
    decode_one(P, b, gi, wlim, hlim, x1, y1, x2, y2);
    float* o = boxes + ((size_t)b * PRE + r) * 4;
    o[0] = x1; o[1] = y1; o[2] = x2; o[3] = y2;
  }
}

// ---------- kernel D: IoU bitmasks — columns cb<JMAX only, transposed [cb][row] ----------
__global__ void k_mask(const float* boxes, unsigned long long* mask) {
  int cb = blockIdx.x, rb = blockIdx.y, b = blockIdx.z;
  if (rb > cb) return;                      // lower triangle never read
  int t = threadIdx.x;  // 64 threads
  __shared__ float cx1[64], cy1[64], cx2[64], cy2[64], car[64];
  int j0 = cb * 64;
  int jn = min(64, PRE - j0);
  if (t < jn) {
    const float* bj = boxes + ((size_t)b * PRE + j0 + t) * 4;
    float a1 = bj[0], b1 = bj[1], a2 = bj[2], b2 = bj[3];
    cx1[t] = a1; cy1[t] = b1; cx2[t] = a2; cy2[t] = b2;
    car[t] = area_of(a1, b1, a2, b2);
  }
  __syncthreads();
  int i = rb * 64 + t;
  if (i >= PRE) return;
  const float* bi = boxes + ((size_t)b * PRE + i) * 4;
  float x1 = bi[0], y1 = bi[1], x2 = bi[2], y2 = bi[3];
  float ai = area_of(x1, y1, x2, y2);
  unsigned long long bits = 0;
  if (cb > rb) {
    for (int jj = 0; jj < jn; ++jj)
      if (iou_gt(x1, y1, x2, y2, ai, cx1[jj], cy1[jj], cx2[jj], cy2[jj], car[jj]))
        bits |= (1ull << jj);
  } else {                                  // diagonal block: j > i only
    for (int jj = t + 1; jj < jn; ++jj)
      if (iou_gt(x1, y1, x2, y2, ai, cx1[jj], cy1[jj], cx2[jj], cy2[jj], car[jj]))
        bits |= (1ull << jj);
  }
  mask[((size_t)b * JMAX + cb) * PREP + i] = bits;   // coalesced over i
}

// ---------- survivor/suppressed key ----------
__device__ __forceinline__ unsigned long long make_key(const float* selScore,
                                                       int b, int i, bool sup) {
  float s = sup ? NEGF : selScore[(size_t)b * PRE + i];
  unsigned tiev = 0xFFFFFFFFu - (unsigned)(b * 8192 + i);
  return ((unsigned long long)forder(s) << 32) | (unsigned long long)tiev;
}

// ---------- kernel E: greedy scan + post-NMS compaction (fused, single wave) ----------
// Scan: sparse diag chain (only nonzero-diag rows visited — provably identical
// since diag==0 rows cannot change st). Early stop when >= POST survivors.
// Compaction (was k_postc): survivor keys all exceed suppressed keys and are
// slot-order descending, so top-1000 = first 1000 survivors; fill with
// suppressed keys in index order if short. Uses s_alive only; rem deleted.
__global__ __launch_bounds__(64, 1) void k_scan(const float* __restrict__ boxes,
                                                const unsigned long long* __restrict__ mask,
                                                const float* __restrict__ selScore,
                                                unsigned long long* __restrict__ pk) {
  const int b = blockIdx.x, l = threadIdx.x;   // 64 lanes
  const unsigned long long* m = mask + (size_t)b * JMAX * PREP;

  __shared__ float4 s_box[PRE];                // fallback only (96 KB)
  __shared__ unsigned long long s_alive[MWORDS];

  for (int i = l; i < MWORDS; i += 64) s_alive[i] = 0ull;   // trailing words = dead

  unsigned long long colAlive = 0;             // bit k = alive(row 64k+l), k < JMAX
  int count = 0;
  bool loaded = false;
  int j = 0;

  for (; j < MWORDS; ++j) {
    unsigned long long word, diag;
    if (j < JMAX) {
      const unsigned long long* mcol = m + (size_t)j * PREP;
      unsigned long long acc = 0;
      int k = 0;
      for (; k + 8 <= j; k += 8) {             // 8 independent loads -> 1 vmcnt batch
        unsigned long long v0 = mcol[(k + 0) * 64 + l];
        unsigned long long v1 = mcol[(k + 1) * 64 + l];
        unsigned long long v2 = mcol[(k + 2) * 64 + l];
        unsigned long long v3 = mcol[(k + 3) * 64 + l];
        unsigned long long v4 = mcol[(k + 4) * 64 + l];
        unsigned long long v5 = mcol[(k + 5) * 64 + l];
        unsigned long long v6 = mcol[(k + 6) * 64 + l];
        unsigned long long v7 = mcol[(k + 7) * 64 + l];
        acc |= v0 & (0ull - ((colAlive >> (k + 0)) & 1ull));
        acc |= v1 & (0ull - ((colAlive >> (k + 1)) & 1ull));
        acc |= v2 & (0ull - ((colAlive >> (k + 2)) & 1ull));
        acc |= v3 & (0ull - ((colAlive >> (k + 3)) & 1ull));
        acc |= v4 & (0ull - ((colAlive >> (k + 4)) & 1ull));
        acc |= v5 & (0ull - ((colAlive >> (k + 5)) & 1ull));
        acc |= v6 & (0ull - ((colAlive >> (k + 6)) & 1ull));
        acc |= v7 & (0ull - ((colAlive >> (k + 7)) & 1ull));
      }
      for (; k < j; ++k)
        acc |= mcol[k * 64 + l] & (0ull - ((colAlive >> k) & 1ull));
      diag = mcol[j * 64 + l];
      #pragma unroll
      for (int off = 32; off > 0; off >>= 1) acc |= __shfl_xor(acc, off, 64);
      word = acc;
    } else {
      if (!loaded) {                           // wave-uniform lazy box load
        for (int r = l; r < PRE; r += 64)
          s_box[r] = ((const float4*)boxes)[(size_t)b * PRE + r];
        loaded = true;
      }
      int col = j * 64 + l;
      bool supp = false;
      if (col < PRE) {
        float4 c4 = s_box[col];
        float ca = area_of(c4.x, c4.y, c4.z, c4.w);
        for (int r = 0; r < j * 64; ++r) {
          if ((s_alive[r >> 6] >> (r & 63)) & 1ull) {
            float4 r4 = s_box[r];
            supp |= iou_gt(r4.x, r4.y, r4.z, r4.w,
                           area_of(r4.x, r4.y, r4.z, r4.w),
                           c4.x, c4.y, c4.z, c4.w, ca);
          }
        }
      }
      word = __ballot(supp);
      diag = 0ull;
      int row = j * 64 + l;
      int jn = min(64, PRE - j * 64);
      if (row < PRE) {
        float4 b4 = s_box[row];
        float ai = area_of(b4.x, b4.y, b4.z, b4.w);
        for (int jj = l + 1; jj < jn; ++jj) {
          float4 c4 = s_box[j * 64 + jj];
          if (iou_gt(b4.x, b4.y, b4.z, b4.w, ai,
                     c4.x, c4.y, c4.z, c4.w,
                     area_of(c4.x, c4.y, c4.z, c4.w)))
            diag |= (1ull << jj);
        }
      }
    }

    // SPARSE serial chain: visit only rows with nonzero diag, in order
    unsigned long long nz = __ballot(diag != 0ull);
    unsigned vdlo = (unsigned)diag, vdhi = (unsigned)(diag >> 32);
    unsigned slo = __builtin_amdgcn_readfirstlane((unsigned)word);
    unsigned shi = __builtin_amdgcn_readfirstlane((unsigned)(word >> 32));
    unsigned long long st = ((unsigned long long)shi << 32) | slo;
    while (nz) {
      int kk = (int)__builtin_ctzll(nz);
      nz &= nz - 1ull;
      if (!((st >> kk) & 1ull)) {
        unsigned dlo = __builtin_amdgcn_readlane(vdlo, kk);
        unsigned dhi = __builtin_amdgcn_readlane(vdhi, kk);
        st |= ((unsigned long long)dhi << 32) | dlo;
      }
    }
    unsigned long long vmask = (j < MWORDS - 1) ? ~0ull : ((1ull << 48) - 1ull);
    unsigned long long alive = (~st) & vmask;
    if (l == 0) s_alive[j] = alive;
    if (j < 64) colAlive |= ((alive >> l) & 1ull) << j;
    count += __popcll(alive);                  // uniform
    if (count >= POST) break;
  }

  // ---- fused post-NMS top-1000 compaction (s_alive-only; unprocessed = dead)
  const unsigned long long lastmask = (1ull << 48) - 1ull;
  int base = 0;
  for (int w = 0; w < MWORDS && base < POST; ++w) {
    unsigned long long alive = s_alive[w];     // 0 for unprocessed words
    int pos = base + __popcll(alive & ((1ull << l) - 1ull));
    if (((alive >> l) & 1ull) && pos < POST)
      pk[(size_t)b * POST + pos] = make_key(selScore, b, w * 64 + l, false);
    base += __popcll(alive);
  }
  if (base < POST) {                           // rare: fewer than 1000 survivors
    int fill = base;
    for (int w = 0; w < MWORDS && fill < POST; ++w) {
      unsigned long long dead = ~s_alive[w];
      if (w == MWORDS - 1) dead &= lastmask;
      int pos = fill + __popcll(dead & ((1ull << l) - 1ull));
      if (((dead >> l) & 1ull) && pos < POST)
        pk[(size_t)b * POST + pos] = make_key(selScore, b, w * 64 + l, true);
      fill += __popcll(dead);
    }
  }
}

// ---------- kernel G: global top-1000 of 4000 — full rank + gather (fused) ----------
__global__ __launch_bounds__(1024) void k_final(const unsigned long long* __restrict__ pk,
                                                const float* __restrict__ boxes,
                                                float* __restrict__ out) {
  const int sc = blockIdx.x;                   // 4 blocks
  const int slot = sc * 1024 + threadIdx.x;
  __shared__ __align__(16) unsigned long long tile[1024];
  unsigned long long my = (slot < B_ * POST) ? pk[slot] : 0ull;
  int r = 0;
  for (int jc = 0; jc < 4; ++jc) {
    __syncthreads();
    int ji = jc * 1024 + threadIdx.x;
    tile[threadIdx.x] = (ji < B_ * POST) ? pk[ji] : 0ull;
    __syncthreads();
    const ulonglong2* t2 = (const ulonglong2*)tile;
    #pragma unroll 8
    for (int t = 0; t < 512; ++t) { ulonglong2 v = t2[t]; r += (v.x > my) + (v.y > my); }
  }
  if (slot < B_ * POST && r < POST) {
    unsigned v = 0xFFFFFFFFu - (unsigned)(my & 0xFFFFFFFFull);
    int b = v >> 13, pos = v & 8191;
    float s = funorder((unsigned)(my >> 32));
    const float* bx = boxes + ((size_t)b * PRE + pos) * 4;
    out[r * 5 + 0] = (float)b;
    out[r * 5 + 1] = bx[0];
    out[r * 5 + 2] = bx[1];
    out[r * 5 + 3] = bx[2];
    out[r * 5 + 4] = bx[3];
    out[5 * POST + r] = s;
  }
}

// ---------- workspace layout (bytes, all 16-aligned) ----------
static constexpr size_t OFF_SELS = 0;                                    // B*PRE f32
static constexpr size_t OFF_BOX  = OFF_SELS + (size_t)B_ * PRE * 4;      // B*PRE*4 f32
static constexpr size_t OFF_MASK = OFF_BOX  + (size_t)B_ * PRE * 16;     // B*JMAX*PREP u64
static constexpr size_t OFF_PK   = OFF_MASK + (size_t)B_ * JMAX * PREP * 8; // B*POST u64
static constexpr size_t OFF_HIST = OFF_PK   + (size_t)B_ * POST * 8;     // B*HGRP*NBINS i32
static constexpr size_t OFF_CNT  = OFF_HIST + (size_t)B_ * HGRP * NBINS * 4; // B*CNTSTRIDE i32
static constexpr size_t OFF_CUTM = OFF_CNT  + (size_t)B_ * CNTSTRIDE * 4;// B*2 i32 (pad 32)
static constexpr size_t OFF_CAND = OFF_CUTM + 32;                        // B*NCAND u64
static constexpr size_t OFF_RKA  = OFF_CAND + (size_t)B_ * NCAND * 8;    // B*NCAND i32

extern "C" void kernel_launch(void* const* d_in, const int* in_sizes, int n_in,
                              void* d_out, int out_size, void* d_ws, size_t ws_size,
                              hipStream_t stream) {
  Ptrs P;
  bool interleaved = (n_in >= 2) && (in_sizes[1] == 2 * in_sizes[0]);
  for (int l = 0; l < 5; ++l) {
    if (interleaved) { P.cls[l] = (const float*)d_in[2 * l]; P.bbox[l] = (const float*)d_in[2 * l + 1]; }
    else             { P.cls[l] = (const float*)d_in[l];     P.bbox[l] = (const float*)d_in[5 + l]; }
  }
  const float* im_info = (const float*)d_in[10];

  char* ws = (char*)d_ws;
  float*              selScore = (float*)(ws + OFF_SELS);
  float*              selBoxes = (float*)(ws + OFF_BOX);
  unsigned long long* maskBuf  = (unsigned long long*)(ws + OFF_MASK);
  unsigned long long* postKeys = (unsigned long long*)(ws + OFF_PK);
  int*                histBuf  = (int*)(ws + OFF_HIST);
  int*                cntBuf   = (int*)(ws + OFF_CNT);
  int*                cutMBuf  = (int*)(ws + OFF_CUTM);
  unsigned long long* candBuf  = (unsigned long long*)(ws + OFF_CAND);
  int*                rankA    = (int*)(ws + OFF_RKA);
  float*              out      = (float*)d_out;

  k_hist<<<dim3(HGRP, B_), 1024, 0, stream>>>(P, histBuf);
  k_cut<<<B_, NBINS, 0, stream>>>(histBuf, cutMBuf, cntBuf);
  k_compact<<<dim3((N1 + 255) / 256, B_), 256, 0, stream>>>(P, cutMBuf, cntBuf, candBuf);
  k_rankp<<<dim3(8, B_), 1024, 0, stream>>>(candBuf, cutMBuf, rankA);
  k_rankdec<<<dim3(NCAND / 256, B_), 256, 0, stream>>>(P, im_info, candBuf, rankA, cutMBuf, selScore, selBoxes);
  k_mask<<<dim3(JMAX, JMAX, B_), 64, 0, stream>>>(selBoxes, maskBuf);
  k_scan<<<B_, 64, 0, stream>>>(selBoxes, maskBuf, selScore, postKeys);
  k_final<<<4, 1024, 0, stream>>>(postKeys, selBoxes, out);
}

// Round 17
// 197.619 us; speedup vs baseline: 1.5689x; 1.5689x over previous
//
#include <hip/hip_runtime.h>
#include <stdint.h>
#include <math.h>

static constexpr int B_   = 4;
static constexpr int N1   = 255780;   // total anchors per image across 5 levels
static constexpr int PRE  = 6000;
static constexpr int PREP = 6016;     // padded rows (multiple of 64)
static constexpr int POST = 1000;
static constexpr int MWORDS = 94;     // ceil(6000/64)
static constexpr int JMAX = 40;       // precomputed mask columns (stop measured ~24)
static constexpr int NCAND = 8192;    // candidate capacity per image
static constexpr int NBINS = 512;     // histogram bins
static constexpr int HGRP = 64;       // histogram partial groups per image
static constexpr int CNTSTRIDE = 32;  // ints; 128B — one cache line per image
static constexpr float NEGF = -1000000000.0f;

__device__ __constant__ int c_OFF[6] = {0,192000,240000,252000,255000,255780};
__device__ __constant__ int c_H[5]   = {200,100,50,25,13};
__device__ __constant__ int c_W[5]   = {320,160,80,40,20};
__device__ __constant__ int c_S[5]   = {4,8,16,32,64};

struct Ptrs { const float* cls[5]; const float* bbox[5]; };

// ---------- helpers ----------
__device__ __forceinline__ unsigned forder(float f) {
  unsigned u = __float_as_uint(f);
  return (u & 0x80000000u) ? ~u : (u | 0x80000000u);
}
__device__ __forceinline__ float funorder(unsigned u) {
  u = (u & 0x80000000u) ? (u & 0x7FFFFFFFu) : ~u;
  return __uint_as_float(u);
}
__device__ __forceinline__ int bucket_of(float s) {
  int bk = (int)(s * (float)NBINS);
  return max(0, min(NBINS - 1, bk));
}

// Exact division-free IoU test:  rn(inter/uni) > 0.7f  ⟺  inter ≥ m·uni,
// m = 0.7f + 2^-25 (midpoint to the next float; 0.7f mantissa is odd so the
// tie rounds UP). m(25b)×uni(24b) ≤ 49 bits → double product exact. uni > 0.
__device__ __forceinline__ bool iou_gt(float x1, float y1, float x2, float y2, float ai,
                                       float bx1, float by1, float bx2, float by2, float aj) {
  float xx1 = fmaxf(x1, bx1), yy1 = fmaxf(y1, by1);
  float xx2 = fminf(x2, bx2), yy2 = fminf(y2, by2);
  float ww = fmaxf(__fadd_rn(__fsub_rn(xx2, xx1), 1.0f), 0.0f);
  float hh = fmaxf(__fadd_rn(__fsub_rn(yy2, yy1), 1.0f), 0.0f);
  float inter = __fmul_rn(ww, hh);
  float uni = __fsub_rn(__fadd_rn(ai, aj), inter);
  return (double)inter >= ((double)0.7f + 0x1p-25) * (double)uni;
}
__device__ __forceinline__ float area_of(float ax1, float ay1, float ax2, float ay2) {
  return __fmul_rn(__fadd_rn(__fsub_rn(ax2, ax1), 1.0f),
                   __fadd_rn(__fsub_rn(ay2, ay1), 1.0f));
}

// score gather (no decode needed: with MIN_SIZE=0 every box is provably valid)
__device__ __forceinline__ float score_of(const Ptrs& P, int b, int i) {
  int lvl = (i >= c_OFF[4]) ? 4 : (i >= c_OFF[3]) ? 3 : (i >= c_OFF[2]) ? 2 : (i >= c_OFF[1]) ? 1 : 0;
  int rem = i - c_OFF[lvl];
  int a = rem % 3;
  int pos = rem / 3;
  size_t hw = (size_t)c_H[lvl] * c_W[lvl];
  return P.cls[lvl][((size_t)b * 6 + 3 + a) * hw + (size_t)pos];
}

// base anchor (legacy +1 convention), double math == numpy float64, rint == np.round
__device__ __forceinline__ void anchor_for(int lvl, int a, float& ax1, float& ay1, float& ax2, float& ay2) {
  int st = c_S[lvl];
  double size = (double)st * (double)st;
  double c = 0.5 * (double)(st - 1);
  double r = (a == 0) ? 0.5 : (a == 1) ? 1.0 : 2.0;
  double ws = rint(sqrt(size / r));
  double hs = rint(ws * r);
  double w2 = ws * 8.0, h2 = hs * 8.0;
  ax1 = (float)(c - 0.5 * (w2 - 1.0));
  ay1 = (float)(c - 0.5 * (h2 - 1.0));
  ax2 = (float)(c + 0.5 * (w2 - 1.0));
  ay2 = (float)(c + 0.5 * (h2 - 1.0));
}

// decode one anchor exactly as the reference (per-op f32 rounding, no FMA)
__device__ __forceinline__ void decode_one(const Ptrs& P, int b, int gi, float wlim, float hlim,
                                           float& x1, float& y1, float& x2, float& y2) {
  int lvl = (gi >= c_OFF[4]) ? 4 : (gi >= c_OFF[3]) ? 3 : (gi >= c_OFF[2]) ? 2 : (gi >= c_OFF[1]) ? 1 : 0;
  int rem = gi - c_OFF[lvl];
  int a = rem % 3;
  int pos = rem / 3;
  int W = c_W[lvl];
  int h = pos / W, w = pos - h * W;
  size_t hw = (size_t)c_H[lvl] * W;
  const float* bb = P.bbox[lvl] + ((size_t)b * 12 + 4 * a) * hw + (size_t)h * W + w;
  float d0 = bb[0], d1 = bb[hw], d2 = bb[2 * hw], d3 = bb[3 * hw];

  float ax1, ay1, ax2, ay2;
  anchor_for(lvl, a, ax1, ay1, ax2, ay2);
  int st = c_S[lvl];
  float sx = (float)(w * st), sy = (float)(h * st);
  ax1 += sx; ax2 += sx; ay1 += sy; ay2 += sy;   // exact integers

  float aw  = __fadd_rn(__fsub_rn(ax2, ax1), 1.0f);
  float ah  = __fadd_rn(__fsub_rn(ay2, ay1), 1.0f);
  float acx = __fadd_rn(ax1, __fmul_rn(0.5f, __fsub_rn(aw, 1.0f)));
  float acy = __fadd_rn(ay1, __fmul_rn(0.5f, __fsub_rn(ah, 1.0f)));
  float ew  = (float)exp((double)d2);
  float eh  = (float)exp((double)d3);
  float pcx = __fadd_rn(__fmul_rn(d0, aw), acx);
  float pcy = __fadd_rn(__fmul_rn(d1, ah), acy);
  float pw  = __fmul_rn(ew, aw);
  float ph  = __fmul_rn(eh, ah);
  float hwf = __fmul_rn(0.5f, __fsub_rn(pw, 1.0f));
  float hhf = __fmul_rn(0.5f, __fsub_rn(ph, 1.0f));
  x1 = __fsub_rn(pcx, hwf);
  x2 = __fadd_rn(pcx, hwf);
  y1 = __fsub_rn(pcy, hhf);
  y2 = __fadd_rn(pcy, hhf);
  x1 = fminf(fmaxf(x1, 0.0f), wlim);
  x2 = fminf(fmaxf(x2, 0.0f), wlim);
  y1 = fminf(fmaxf(y1, 0.0f), hlim);
  y2 = fminf(fmaxf(y2, 0.0f), hlim);
}

// ---------- kernel A: per-group partial histograms (no init, no global atomics) ----------
__global__ __launch_bounds__(1024) void k_hist(Ptrs P, int* hist) {
  const int b = blockIdx.y, g = blockIdx.x;    // HGRP groups per image
  __shared__ int h[NBINS];
  for (int k = threadIdx.x; k < NBINS; k += 1024) h[k] = 0;
  __syncthreads();
  const int step = HGRP * 1024;
  for (int i = g * 1024 + threadIdx.x; i < N1; i += step)
    atomicAdd(&h[bucket_of(score_of(P, b, i))], 1);
  __syncthreads();
  for (int k = threadIdx.x; k < NBINS; k += 1024)
    hist[((size_t)b * HGRP + g) * NBINS + k] = h[k];
}

// ---------- kernel B1: cutoff bin per image (sum partials + suffix-sum); zeroes cnt ----------
__global__ __launch_bounds__(NBINS) void k_cut(const int* hist, int* cutM, int* cnt) {
  int b = blockIdx.x, t = threadIdx.x;
  __shared__ int ts[NBINS];
  int mine = 0;
  for (int g = 0; g < HGRP; ++g) mine += hist[((size_t)b * HGRP + g) * NBINS + t];
  ts[t] = mine;
  if (t == 0) cnt[b * CNTSTRIDE] = 0;          // zero compaction counter (pre-k_compact)
  __syncthreads();
  for (int off = 1; off < NBINS; off <<= 1) {
    int v = ts[t] + ((t + off < NBINS) ? ts[t + off] : 0);
    __syncthreads();
    ts[t] = v;
    __syncthreads();
  }
  int nxt = (t + 1 < NBINS) ? ts[t + 1] : 0;
  if (ts[t] >= PRE && nxt < PRE) { cutM[b * 2] = t; cutM[b * 2 + 1] = ts[t]; }
}

// ---------- kernel B2: compact candidate keys — block-aggregated atomics ----------
__global__ __launch_bounds__(256) void k_compact(Ptrs P, const int* __restrict__ cutM, int* cnt,
                                                 unsigned long long* __restrict__ cand) {
  const int i = blockIdx.x * blockDim.x + threadIdx.x;
  const int b = blockIdx.y;
  const int wid = threadIdx.x >> 6;
  __shared__ int wcnts[4], wbase[4];

  int cut = cutM[b * 2];
  bool isc = false;
  float s = 0.0f;
  if (i < N1) {
    s = score_of(P, b, i);
    isc = bucket_of(s) >= cut;
  }
  unsigned long long ball = __ballot(isc);
  if ((threadIdx.x & 63) == 0) wcnts[wid] = __popcll(ball);
  __syncthreads();
  if (threadIdx.x == 0) {
    int tot = wcnts[0] + wcnts[1] + wcnts[2] + wcnts[3];
    int base = tot ? atomicAdd(&cnt[b * CNTSTRIDE], tot) : 0;
    wbase[0] = base;
    wbase[1] = base + wcnts[0];
    wbase[2] = base + wcnts[0] + wcnts[1];
    wbase[3] = base + wcnts[0] + wcnts[1] + wcnts[2];
  }
  __syncthreads();
  if (isc) {
    unsigned long long lower = ball & ((1ull << (threadIdx.x & 63)) - 1ull);
    int p = wbase[wid] + __popcll(lower);
    if (p < NCAND)
      cand[(size_t)b * NCAND + p] = ((unsigned long long)forder(s) << 32) |
                                    (unsigned long long)(0xFFFFFFFFu - (unsigned)i);
  }
}

// ---------- kernel B3a: PARTIAL ranks, one tile pair per block (256 blocks) ----------
// No atomics, no zero-init: block (sc,jc) writes its partial rank to its own
// slice rankP[(b*8+jc)*NCAND + slot]. Blocks with sc/jc tile beyond M exit
// without writing; k_rankdec sums only jc < ceil(M/1024) and slots < M, so
// stale memory is never observed. Masked tile loads keep stale cand inert.
__global__ __launch_bounds__(1024) void k_rankp(const unsigned long long* __restrict__ cand,
                                                const int* __restrict__ cutM,
                                                int* __restrict__ rankP) {
  const int b = blockIdx.y;
  const int sc = blockIdx.x >> 3, jc = blockIdx.x & 7;
  const int M = min(cutM[b * 2 + 1], NCAND);
  if (sc * 1024 >= M || jc * 1024 >= M) return;
  __shared__ __align__(16) unsigned long long tile[1024];
  const unsigned long long* src = cand + (size_t)b * NCAND;
  int ji = jc * 1024 + threadIdx.x;
  tile[threadIdx.x] = (ji < M) ? src[ji] : 0ull;
  __syncthreads();
  const int slot = sc * 1024 + threadIdx.x;
  unsigned long long my = (slot < M) ? src[slot] : ~0ull;
  int r = 0;
  const ulonglong2* t2 = (const ulonglong2*)tile;
  #pragma unroll 8
  for (int t = 0; t < 512; ++t) { ulonglong2 v = t2[t]; r += (v.x > my) + (v.y > my); }
  rankP[((size_t)(b * 8 + jc)) * NCAND + slot] = r;
}

// ---------- kernel B3b+C fused: sum partials, scatter by rank, decode boxes ----------
__global__ void k_rankdec(Ptrs P, const float* im_info,
                          const unsigned long long* cand, const int* rankP,
                          const int* cutM, float* selScore, float* boxes) {
  int b = blockIdx.y, slot = blockIdx.x * 256 + threadIdx.x;
  const int M = min(cutM[b * 2 + 1], NCAND);
  if (slot >= M) return;                       // stale slots never read
  const int njc = (M + 1023) >> 10;
  int r = 0;
  for (int jc = 0; jc < njc; ++jc)
    r += rankP[((size_t)(b * 8 + jc)) * NCAND + slot];
  if (r < PRE) {
    unsigned long long my = cand[(size_t)b * NCAND + slot];
    int gi = (int)(0xFFFFFFFFu - (unsigned)(my & 0xFFFFFFFFull));
    selScore[(size_t)b * PRE + r] = funorder((unsigned)(my >> 32));
    float wlim = __fsub_rn(im_info[b * 3 + 1], 1.0f);
    float hlim = __fsub_rn(im_info[b * 3 + 0], 1.0f);
    float x1, y1, x2, y2;
    decode_one(P, b, gi, wlim, hlim, x1, y1, x2, y2);
    float* o = boxes + ((size_t)b * PRE + r) * 4;
    o[0] = x1; o[1] = y1; o[2] = x2; o[3] = y2;
  }
}

// ---------- kernel D: IoU bitmasks — columns cb<JMAX only, transposed [cb][row] ----------
__global__ void k_mask(const float* boxes, unsigned long long* mask) {
  int cb = blockIdx.x, rb = blockIdx.y, b = blockIdx.z;
  if (rb > cb) return;                      // lower triangle never read
  int t = threadIdx.x;  // 64 threads
  __shared__ float cx1[64], cy1[64], cx2[64], cy2[64], car[64];
  int j0 = cb * 64;
  int jn = min(64, PRE - j0);
  if (t < jn) {
    const float* bj = boxes + ((size_t)b * PRE + j0 + t) * 4;
    float a1 = bj[0], b1 = bj[1], a2 = bj[2], b2 = bj[3];
    cx1[t] = a1; cy1[t] = b1; cx2[t] = a2; cy2[t] = b2;
    car[t] = area_of(a1, b1, a2, b2);
  }
  __syncthreads();
  int i = rb * 64 + t;
  if (i >= PRE) return;
  const float* bi = boxes + ((size_t)b * PRE + i) * 4;
  float x1 = bi[0], y1 = bi[1], x2 = bi[2], y2 = bi[3];
  float ai = area_of(x1, y1, x2, y2);
  unsigned long long bits = 0;
  if (cb > rb) {
    for (int jj = 0; jj < jn; ++jj)
      if (iou_gt(x1, y1, x2, y2, ai, cx1[jj], cy1[jj], cx2[jj], cy2[jj], car[jj]))
        bits |= (1ull << jj);
  } else {                                  // diagonal block: j > i only
    for (int jj = t + 1; jj < jn; ++jj)
      if (iou_gt(x1, y1, x2, y2, ai, cx1[jj], cy1[jj], cx2[jj], cy2[jj], car[jj]))
        bits |= (1ull << jj);
  }
  mask[((size_t)b * JMAX + cb) * PREP + i] = bits;   // coalesced over i
}

// ---------- survivor/suppressed key ----------
__device__ __forceinline__ unsigned long long make_key(const float* selScore,
                                                       int b, int i, bool sup) {
  float s = sup ? NEGF : selScore[(size_t)b * PRE + i];
  unsigned tiev = 0xFFFFFFFFu - (unsigned)(b * 8192 + i);
  return ((unsigned long long)forder(s) << 32) | (unsigned long long)tiev;
}

// ---------- kernel E: greedy scan + post-NMS compaction (fused, single wave) ----------
__global__ __launch_bounds__(64, 1) void k_scan(const float* __restrict__ boxes,
                                                const unsigned long long* __restrict__ mask,
                                                const float* __restrict__ selScore,
                                                unsigned long long* __restrict__ pk) {
  const int b = blockIdx.x, l = threadIdx.x;   // 64 lanes
  const unsigned long long* m = mask + (size_t)b * JMAX * PREP;

  __shared__ float4 s_box[PRE];                // fallback only (96 KB)
  __shared__ unsigned long long s_alive[MWORDS];

  for (int i = l; i < MWORDS; i += 64) s_alive[i] = 0ull;   // trailing words = dead

  unsigned long long colAlive = 0;             // bit k = alive(row 64k+l), k < JMAX
  int count = 0;
  bool loaded = false;
  int j = 0;

  for (; j < MWORDS; ++j) {
    unsigned long long word, diag;
    if (j < JMAX) {
      const unsigned long long* mcol = m + (size_t)j * PREP;
      unsigned long long acc = 0;
      int k = 0;
      for (; k + 8 <= j; k += 8) {             // 8 independent loads -> 1 vmcnt batch
        unsigned long long v0 = mcol[(k + 0) * 64 + l];
        unsigned long long v1 = mcol[(k + 1) * 64 + l];
        unsigned long long v2 = mcol[(k + 2) * 64 + l];
        unsigned long long v3 = mcol[(k + 3) * 64 + l];
        unsigned long long v4 = mcol[(k + 4) * 64 + l];
        unsigned long long v5 = mcol[(k + 5) * 64 + l];
        unsigned long long v6 = mcol[(k + 6) * 64 + l];
        unsigned long long v7 = mcol[(k + 7) * 64 + l];
        acc |= v0 & (0ull - ((colAlive >> (k + 0)) & 1ull));
        acc |= v1 & (0ull - ((colAlive >> (k + 1)) & 1ull));
        acc |= v2 & (0ull - ((colAlive >> (k + 2)) & 1ull));
        acc |= v3 & (0ull - ((colAlive >> (k + 3)) & 1ull));
        acc |= v4 & (0ull - ((colAlive >> (k + 4)) & 1ull));
        acc |= v5 & (0ull - ((colAlive >> (k + 5)) & 1ull));
        acc |= v6 & (0ull - ((colAlive >> (k + 6)) & 1ull));
        acc |= v7 & (0ull - ((colAlive >> (k + 7)) & 1ull));
      }
      for (; k < j; ++k)
        acc |= mcol[k * 64 + l] & (0ull - ((colAlive >> k) & 1ull));
      diag = mcol[j * 64 + l];
      #pragma unroll
      for (int off = 32; off > 0; off >>= 1) acc |= __shfl_xor(acc, off, 64);
      word = acc;
    } else {
      if (!loaded) {                           // wave-uniform lazy box load
        for (int r = l; r < PRE; r += 64)
          s_box[r] = ((const float4*)boxes)[(size_t)b * PRE + r];
        loaded = true;
      }
      int col = j * 64 + l;
      bool supp = false;
      if (col < PRE) {
        float4 c4 = s_box[col];
        float ca = area_of(c4.x, c4.y, c4.z, c4.w);
        for (int r = 0; r < j * 64; ++r) {
          if ((s_alive[r >> 6] >> (r & 63)) & 1ull) {
            float4 r4 = s_box[r];
            supp |= iou_gt(r4.x, r4.y, r4.z, r4.w,
                           area_of(r4.x, r4.y, r4.z, r4.w),
                           c4.x, c4.y, c4.z, c4.w, ca);
          }
        }
      }
      word = __ballot(supp);
      diag = 0ull;
      int row = j * 64 + l;
      int jn = min(64, PRE - j * 64);
      if (row < PRE) {
        float4 b4 = s_box[row];
        float ai = area_of(b4.x, b4.y, b4.z, b4.w);
        for (int jj = l + 1; jj < jn; ++jj) {
          float4 c4 = s_box[j * 64 + jj];
          if (iou_gt(b4.x, b4.y, b4.z, b4.w, ai,
                     c4.x, c4.y, c4.z, c4.w,
                     area_of(c4.x, c4.y, c4.z, c4.w)))
            diag |= (1ull << jj);
        }
      }
    }

    // SPARSE serial chain: visit only rows with nonzero diag, in order
    unsigned long long nz = __ballot(diag != 0ull);
    unsigned vdlo = (unsigned)diag, vdhi = (unsigned)(diag >> 32);
    unsigned slo = __builtin_amdgcn_readfirstlane((unsigned)word);
    unsigned shi = __builtin_amdgcn_readfirstlane((unsigned)(word >> 32));
    unsigned long long st = ((unsigned long long)shi << 32) | slo;
    while (nz) {
      int kk = (int)__builtin_ctzll(nz);
      nz &= nz - 1ull;
      if (!((st >> kk) & 1ull)) {
        unsigned dlo = __builtin_amdgcn_readlane(vdlo, kk);
        unsigned dhi = __builtin_amdgcn_readlane(vdhi, kk);
        st |= ((unsigned long long)dhi << 32) | dlo;
      }
    }
    unsigned long long vmask = (j < MWORDS - 1) ? ~0ull : ((1ull << 48) - 1ull);
    unsigned long long alive = (~st) & vmask;
    if (l == 0) s_alive[j] = alive;
    if (j < 64) colAlive |= ((alive >> l) & 1ull) << j;
    count += __popcll(alive);                  // uniform
    if (count >= POST) break;
  }

  // ---- fused post-NMS top-1000 compaction (s_alive-only; unprocessed = dead)
  const unsigned long long lastmask = (1ull << 48) - 1ull;
  int base = 0;
  for (int w = 0; w < MWORDS && base < POST; ++w) {
    unsigned long long alive = s_alive[w];     // 0 for unprocessed words
    int pos = base + __popcll(alive & ((1ull << l) - 1ull));
    if (((alive >> l) & 1ull) && pos < POST)
      pk[(size_t)b * POST + pos] = make_key(selScore, b, w * 64 + l, false);
    base += __popcll(alive);
  }
  if (base < POST) {                           // rare: fewer than 1000 survivors
    int fill = base;
    for (int w = 0; w < MWORDS && fill < POST; ++w) {
      unsigned long long dead = ~s_alive[w];
      if (w == MWORDS - 1) dead &= lastmask;
      int pos = fill + __popcll(dead & ((1ull << l) - 1ull));
      if (((dead >> l) & 1ull) && pos < POST)
        pk[(size_t)b * POST + pos] = make_key(selScore, b, w * 64 + l, true);
      fill += __popcll(dead);
    }
  }
}

// ---------- kernel G: global top-1000 of 4000 — full rank + gather (fused) ----------
__global__ __launch_bounds__(1024) void k_final(const unsigned long long* __restrict__ pk,
                                                const float* __restrict__ boxes,
                                                float* __restrict__ out) {
  const int sc = blockIdx.x;                   // 4 blocks
  const int slot = sc * 1024 + threadIdx.x;
  __shared__ __align__(16) unsigned long long tile[1024];
  unsigned long long my = (slot < B_ * POST) ? pk[slot] : 0ull;
  int r = 0;
  for (int jc = 0; jc < 4; ++jc) {
    __syncthreads();
    int ji = jc * 1024 + threadIdx.x;
    tile[threadIdx.x] = (ji < B_ * POST) ? pk[ji] : 0ull;
    __syncthreads();
    const ulonglong2* t2 = (const ulonglong2*)tile;
    #pragma unroll 8
    for (int t = 0; t < 512; ++t) { ulonglong2 v = t2[t]; r += (v.x > my) + (v.y > my); }
  }
  if (slot < B_ * POST && r < POST) {
    unsigned v = 0xFFFFFFFFu - (unsigned)(my & 0xFFFFFFFFull);
    int b = v >> 13, pos = v & 8191;
    float s = funorder((unsigned)(my >> 32));
    const float* bx = boxes + ((size_t)b * PRE + pos) * 4;
    out[r * 5 + 0] = (float)b;
    out[r * 5 + 1] = bx[0];
    out[r * 5 + 2] = bx[1];
    out[r * 5 + 3] = bx[2];
    out[r * 5 + 4] = bx[3];
    out[5 * POST + r] = s;
  }
}

// ---------- workspace layout (bytes, all 16-aligned) ----------
static constexpr size_t OFF_SELS = 0;                                    // B*PRE f32
static constexpr size_t OFF_BOX  = OFF_SELS + (size_t)B_ * PRE * 4;      // B*PRE*4 f32
static constexpr size_t OFF_MASK = OFF_BOX  + (size_t)B_ * PRE * 16;     // B*JMAX*PREP u64
static constexpr size_t OFF_PK   = OFF_MASK + (size_t)B_ * JMAX * PREP * 8; // B*POST u64
static constexpr size_t OFF_HIST = OFF_PK   + (size_t)B_ * POST * 8;     // B*HGRP*NBINS i32
static constexpr size_t OFF_CNT  = OFF_HIST + (size_t)B_ * HGRP * NBINS * 4; // B*CNTSTRIDE i32
static constexpr size_t OFF_CUTM = OFF_CNT  + (size_t)B_ * CNTSTRIDE * 4;// B*2 i32 (pad 32)
static constexpr size_t OFF_CAND = OFF_CUTM + 32;                        // B*NCAND u64
static constexpr size_t OFF_RKP  = OFF_CAND + (size_t)B_ * NCAND * 8;    // B*8*NCAND i32

extern "C" void kernel_launch(void* const* d_in, const int* in_sizes, int n_in,
                              void* d_out, int out_size, void* d_ws, size_t ws_size,
                              hipStream_t stream) {
  Ptrs P;
  bool interleaved = (n_in >= 2) && (in_sizes[1] == 2 * in_sizes[0]);
  for (int l = 0; l < 5; ++l) {
    if (interleaved) { P.cls[l] = (const float*)d_in[2 * l]; P.bbox[l] = (const float*)d_in[2 * l + 1]; }
    else             { P.cls[l] = (const float*)d_in[l];     P.bbox[l] = (const float*)d_in[5 + l]; }
  }
  const float* im_info = (const float*)d_in[10];

  char* ws = (char*)d_ws;
  float*              selScore = (float*)(ws + OFF_SELS);
  float*              selBoxes = (float*)(ws + OFF_BOX);
  unsigned long long* maskBuf  = (unsigned long long*)(ws + OFF_MASK);
  unsigned long long* postKeys = (unsigned long long*)(ws + OFF_PK);
  int*                histBuf  = (int*)(ws + OFF_HIST);
  int*                cntBuf   = (int*)(ws + OFF_CNT);
  int*                cutMBuf  = (int*)(ws + OFF_CUTM);
  unsigned long long* candBuf  = (unsigned long long*)(ws + OFF_CAND);
  int*                rankP    = (int*)(ws + OFF_RKP);
  float*              out      = (float*)d_out;

  k_hist<<<dim3(HGRP, B_), 1024, 0, stream>>>(P, histBuf);
  k_cut<<<B_, NBINS, 0, stream>>>(histBuf, cutMBuf, cntBuf);
  k_compact<<<dim3((N1 + 255) / 256, B_), 256, 0, stream>>>(P, cutMBuf, cntBuf, candBuf);
  k_rankp<<<dim3(64, B_), 1024, 0, stream>>>(candBuf, cutMBuf, rankP);
  k_rankdec<<<dim3(NCAND / 256, B_), 256, 0, stream>>>(P, im_info, candBuf, rankP, cutMBuf, selScore, selBoxes);
  k_mask<<<dim3(JMAX, JMAX, B_), 64, 0, stream>>>(selBoxes, maskBuf);
  k_scan<<<B_, 64, 0, stream>>>(selBoxes, maskBuf, selScore, postKeys);
  k_final<<<4, 1024, 0, stream>>>(postKeys, selBoxes, out);
}

// Round 18
// 177.484 us; speedup vs baseline: 1.7469x; 1.1134x over previous
//
#include <hip/hip_runtime.h>
#include <stdint.h>
#include <math.h>

static constexpr int B_   = 4;
static constexpr int N1   = 255780;   // total anchors per image across 5 levels
static constexpr int PRE  = 6000;
static constexpr int PREP = 6016;     // padded rows (multiple of 64)
static constexpr int POST = 1000;
static constexpr int MWORDS = 94;     // ceil(6000/64)
static constexpr int JMAX = 40;       // precomputed mask columns (stop measured ~24)
static constexpr int NCAND = 8192;    // candidate capacity per image
static constexpr int NBINS = 512;     // histogram bins
static constexpr int HGRP = 64;       // histogram partial groups per image
static constexpr int CNTSTRIDE = 32;  // ints; 128B — one cache line per image
static constexpr float NEGF = -1000000000.0f;

__device__ __constant__ int c_OFF[6] = {0,192000,240000,252000,255000,255780};
__device__ __constant__ int c_H[5]   = {200,100,50,25,13};
__device__ __constant__ int c_W[5]   = {320,160,80,40,20};
__device__ __constant__ int c_S[5]   = {4,8,16,32,64};

struct Ptrs { const float* cls[5]; const float* bbox[5]; };

// ---------- helpers ----------
__device__ __forceinline__ unsigned forder(float f) {
  unsigned u = __float_as_uint(f);
  return (u & 0x80000000u) ? ~u : (u | 0x80000000u);
}
__device__ __forceinline__ float funorder(unsigned u) {
  u = (u & 0x80000000u) ? (u & 0x7FFFFFFFu) : ~u;
  return __uint_as_float(u);
}
__device__ __forceinline__ int bucket_of(float s) {
  int bk = (int)(s * (float)NBINS);
  return max(0, min(NBINS - 1, bk));
}

// Exact division-free IoU test:  rn(inter/uni) > 0.7f  ⟺  inter ≥ m·uni,
// m = 0.7f + 2^-25 (midpoint to the next float; 0.7f mantissa is odd so the
// tie rounds UP). m(25b)×uni(24b) ≤ 49 bits → double product exact. uni > 0.
__device__ __forceinline__ bool iou_gt(float x1, float y1, float x2, float y2, float ai,
                                       float bx1, float by1, float bx2, float by2, float aj) {
  float xx1 = fmaxf(x1, bx1), yy1 = fmaxf(y1, by1);
  float xx2 = fminf(x2, bx2), yy2 = fminf(y2, by2);
  float ww = fmaxf(__fadd_rn(__fsub_rn(xx2, xx1), 1.0f), 0.0f);
  float hh = fmaxf(__fadd_rn(__fsub_rn(yy2, yy1), 1.0f), 0.0f);
  float inter = __fmul_rn(ww, hh);
  float uni = __fsub_rn(__fadd_rn(ai, aj), inter);
  return (double)inter >= ((double)0.7f + 0x1p-25) * (double)uni;
}
__device__ __forceinline__ float area_of(float ax1, float ay1, float ax2, float ay2) {
  return __fmul_rn(__fadd_rn(__fsub_rn(ax2, ax1), 1.0f),
                   __fadd_rn(__fsub_rn(ay2, ay1), 1.0f));
}

// score gather (no decode needed: with MIN_SIZE=0 every box is provably valid)
__device__ __forceinline__ float score_of(const Ptrs& P, int b, int i) {
  int lvl = (i >= c_OFF[4]) ? 4 : (i >= c_OFF[3]) ? 3 : (i >= c_OFF[2]) ? 2 : (i >= c_OFF[1]) ? 1 : 0;
  int rem = i - c_OFF[lvl];
  int a = rem % 3;
  int pos = rem / 3;
  size_t hw = (size_t)c_H[lvl] * c_W[lvl];
  return P.cls[lvl][((size_t)b * 6 + 3 + a) * hw + (size_t)pos];
}

// base anchor (legacy +1 convention), double math == numpy float64, rint == np.round
__device__ __forceinline__ void anchor_for(int lvl, int a, float& ax1, float& ay1, float& ax2, float& ay2) {
  int st = c_S[lvl];
  double size = (double)st * (double)st;
  double c = 0.5 * (double)(st - 1);
  double r = (a == 0) ? 0.5 : (a == 1) ? 1.0 : 2.0;
  double ws = rint(sqrt(size / r));
  double hs = rint(ws * r);
  double w2 = ws * 8.0, h2 = hs * 8.0;
  ax1 = (float)(c - 0.5 * (w2 - 1.0));
  ay1 = (float)(c - 0.5 * (h2 - 1.0));
  ax2 = (float)(c + 0.5 * (w2 - 1.0));
  ay2 = (float)(c + 0.5 * (h2 - 1.0));
}

// decode one anchor exactly as the reference (per-op f32 rounding, no FMA)
__device__ __forceinline__ void decode_one(const Ptrs& P, int b, int gi, float wlim, float hlim,
                                           float& x1, float& y1, float& x2, float& y2) {
  int lvl = (gi >= c_OFF[4]) ? 4 : (gi >= c_OFF[3]) ? 3 : (gi >= c_OFF[2]) ? 2 : (gi >= c_OFF[1]) ? 1 : 0;
  int rem = gi - c_OFF[lvl];
  int a = rem % 3;
  int pos = rem / 3;
  int W = c_W[lvl];
  int h = pos / W, w = pos - h * W;
  size_t hw = (size_t)c_H[lvl] * W;
  const float* bb = P.bbox[lvl] + ((size_t)b * 12 + 4 * a) * hw + (size_t)h * W + w;
  float d0 = bb[0], d1 = bb[hw], d2 = bb[2 * hw], d3 = bb[3 * hw];

  float ax1, ay1, ax2, ay2;
  anchor_for(lvl, a, ax1, ay1, ax2, ay2);
  int st = c_S[lvl];
  float sx = (float)(w * st), sy = (float)(h * st);
  ax1 += sx; ax2 += sx; ay1 += sy; ay2 += sy;   // exact integers

  float aw  = __fadd_rn(__fsub_rn(ax2, ax1), 1.0f);
  float ah  = __fadd_rn(__fsub_rn(ay2, ay1), 1.0f);
  float acx = __fadd_rn(ax1, __fmul_rn(0.5f, __fsub_rn(aw, 1.0f)));
  float acy = __fadd_rn(ay1, __fmul_rn(0.5f, __fsub_rn(ah, 1.0f)));
  float ew  = (float)exp((double)d2);
  float eh  = (float)exp((double)d3);
  float pcx = __fadd_rn(__fmul_rn(d0, aw), acx);
  float pcy = __fadd_rn(__fmul_rn(d1, ah), acy);
  float pw  = __fmul_rn(ew, aw);
  float ph  = __fmul_rn(eh, ah);
  float hwf = __fmul_rn(0.5f, __fsub_rn(pw, 1.0f));
  float hhf = __fmul_rn(0.5f, __fsub_rn(ph, 1.0f));
  x1 = __fsub_rn(pcx, hwf);
  x2 = __fadd_rn(pcx, hwf);
  y1 = __fsub_rn(pcy, hhf);
  y2 = __fadd_rn(pcy, hhf);
  x1 = fminf(fmaxf(x1, 0.0f), wlim);
  x2 = fminf(fmaxf(x2, 0.0f), wlim);
  y1 = fminf(fmaxf(y1, 0.0f), hlim);
  y2 = fminf(fmaxf(y2, 0.0f), hlim);
}

// ---------- kernel A: per-group partial histograms (no init, no global atomics) ----------
__global__ __launch_bounds__(1024) void k_hist(Ptrs P, int* hist) {
  const int b = blockIdx.y, g = blockIdx.x;    // HGRP groups per image
  __shared__ int h[NBINS];
  for (int k = threadIdx.x; k < NBINS; k += 1024) h[k] = 0;
  __syncthreads();
  const int step = HGRP * 1024;
  for (int i = g * 1024 + threadIdx.x; i < N1; i += step)
    atomicAdd(&h[bucket_of(score_of(P, b, i))], 1);
  __syncthreads();
  for (int k = threadIdx.x; k < NBINS; k += 1024)
    hist[((size_t)b * HGRP + g) * NBINS + k] = h[k];
}

// ---------- kernel B1: cutoff bin per image (sum partials + suffix-sum); zeroes cnt ----------
__global__ __launch_bounds__(NBINS) void k_cut(const int* hist, int* cutM, int* cnt) {
  int b = blockIdx.x, t = threadIdx.x;
  __shared__ int ts[NBINS];
  int mine = 0;
  for (int g = 0; g < HGRP; ++g) mine += hist[((size_t)b * HGRP + g) * NBINS + t];
  ts[t] = mine;
  if (t == 0) cnt[b * CNTSTRIDE] = 0;          // zero compaction counter (pre-k_compact)
  __syncthreads();
  for (int off = 1; off < NBINS; off <<= 1) {
    int v = ts[t] + ((t + off < NBINS) ? ts[t + off] : 0);
    __syncthreads();
    ts[t] = v;
    __syncthreads();
  }
  int nxt = (t + 1 < NBINS) ? ts[t + 1] : 0;
  if (ts[t] >= PRE && nxt < PRE) { cutM[b * 2] = t; cutM[b * 2 + 1] = ts[t]; }
}

// ---------- kernel B2: compact candidate keys — block-aggregated atomics ----------
__global__ __launch_bounds__(256) void k_compact(Ptrs P, const int* __restrict__ cutM, int* cnt,
                                                 unsigned long long* __restrict__ cand) {
  const int i = blockIdx.x * blockDim.x + threadIdx.x;
  const int b = blockIdx.y;
  const int wid = threadIdx.x >> 6;
  __shared__ int wcnts[4], wbase[4];

  int cut = cutM[b * 2];
  bool isc = false;
  float s = 0.0f;
  if (i < N1) {
    s = score_of(P, b, i);
    isc = bucket_of(s) >= cut;
  }
  unsigned long long ball = __ballot(isc);
  if ((threadIdx.x & 63) == 0) wcnts[wid] = __popcll(ball);
  __syncthreads();
  if (threadIdx.x == 0) {
    int tot = wcnts[0] + wcnts[1] + wcnts[2] + wcnts[3];
    int base = tot ? atomicAdd(&cnt[b * CNTSTRIDE], tot) : 0;
    wbase[0] = base;
    wbase[1] = base + wcnts[0];
    wbase[2] = base + wcnts[0] + wcnts[1];
    wbase[3] = base + wcnts[0] + wcnts[1] + wcnts[2];
  }
  __syncthreads();
  if (isc) {
    unsigned long long lower = ball & ((1ull << (threadIdx.x & 63)) - 1ull);
    int p = wbase[wid] + __popcll(lower);
    if (p < NCAND)
      cand[(size_t)b * NCAND + p] = ((unsigned long long)forder(s) << 32) |
                                    (unsigned long long)(0xFFFFFFFFu - (unsigned)i);
  }
}

// ---------- kernel B3a: PARTIAL ranks, one tile pair per block (256 blocks) ----------
__global__ __launch_bounds__(1024) void k_rankp(const unsigned long long* __restrict__ cand,
                                                const int* __restrict__ cutM,
                                                int* __restrict__ rankP) {
  const int b = blockIdx.y;
  const int sc = blockIdx.x >> 3, jc = blockIdx.x & 7;
  const int M = min(cutM[b * 2 + 1], NCAND);
  if (sc * 1024 >= M || jc * 1024 >= M) return;
  __shared__ __align__(16) unsigned long long tile[1024];
  const unsigned long long* src = cand + (size_t)b * NCAND;
  int ji = jc * 1024 + threadIdx.x;
  tile[threadIdx.x] = (ji < M) ? src[ji] : 0ull;
  __syncthreads();
  const int slot = sc * 1024 + threadIdx.x;
  unsigned long long my = (slot < M) ? src[slot] : ~0ull;
  int r = 0;
  const ulonglong2* t2 = (const ulonglong2*)tile;
  #pragma unroll 8
  for (int t = 0; t < 512; ++t) { ulonglong2 v = t2[t]; r += (v.x > my) + (v.y > my); }
  rankP[((size_t)(b * 8 + jc)) * NCAND + slot] = r;
}

// ---------- kernel B3b+C fused: sum partials, scatter by rank, decode boxes ----------
__global__ void k_rankdec(Ptrs P, const float* im_info,
                          const unsigned long long* cand, const int* rankP,
                          const int* cutM, float* selScore, float* boxes) {
  int b = blockIdx.y, slot = blockIdx.x * 256 + threadIdx.x;
  const int M = min(cutM[b * 2 + 1], NCAND);
  if (slot >= M) return;                       // stale slots never read
  const int njc = (M + 1023) >> 10;
  int r = 0;
  for (int jc = 0; jc < njc; ++jc)
    r += rankP[((size_t)(b * 8 + jc)) * NCAND + slot];
  if (r < PRE) {
    unsigned long long my = cand[(size_t)b * NCAND + slot];
    int gi = (int)(0xFFFFFFFFu - (unsigned)(my & 0xFFFFFFFFull));
    selScore[(size_t)b * PRE + r] = funorder((unsigned)(my >> 32));
    float wlim = __fsub_rn(im_info[b * 3 + 1], 1.0f);
    float hlim = __fsub_rn(im_info[b * 3 + 0], 1.0f);
    float x1, y1, x2, y2;
    decode_one(P, b, gi, wlim, hlim, x1, y1, x2, y2);
    float* o = boxes + ((size_t)b * PRE + r) * 4;
    o[0] = x1; o[1] = y1; o[2] = x2; o[3] = y2;
  }
}

// ---------- kernel D: IoU bitmasks — columns cb<JMAX only, transposed [cb][row] ----------
__global__ void k_mask(const float* boxes, unsigned long long* mask) {
  int cb = blockIdx.x, rb = blockIdx.y, b = blockIdx.z;
  if (rb > cb) return;                      // lower triangle never read
  int t = threadIdx.x;  // 64 threads
  __shared__ float cx1[64], cy1[64], cx2[64], cy2[64], car[64];
  int j0 = cb * 64;
  int jn = min(64, PRE - j0);
  if (t < jn) {
    const float* bj = boxes + ((size_t)b * PRE + j0 + t) * 4;
    float a1 = bj[0], b1 = bj[1], a2 = bj[2], b2 = bj[3];
    cx1[t] = a1; cy1[t] = b1; cx2[t] = a2; cy2[t] = b2;
    car[t] = area_of(a1, b1, a2, b2);
  }
  __syncthreads();
  int i = rb * 64 + t;
  if (i >= PRE) return;
  const float* bi = boxes + ((size_t)b * PRE + i) * 4;
  float x1 = bi[0], y1 = bi[1], x2 = bi[2], y2 = bi[3];
  float ai = area_of(x1, y1, x2, y2);
  unsigned long long bits = 0;
  if (cb > rb) {
    for (int jj = 0; jj < jn; ++jj)
      if (iou_gt(x1, y1, x2, y2, ai, cx1[jj], cy1[jj], cx2[jj], cy2[jj], car[jj]))
        bits |= (1ull << jj);
  } else {                                  // diagonal block: j > i only
    for (int jj = t + 1; jj < jn; ++jj)
      if (iou_gt(x1, y1, x2, y2, ai, cx1[jj], cy1[jj], cx2[jj], cy2[jj], car[jj]))
        bits |= (1ull << jj);
  }
  mask[((size_t)b * JMAX + cb) * PREP + i] = bits;   // coalesced over i
}

// ---------- survivor/suppressed key ----------
__device__ __forceinline__ unsigned long long make_key(const float* selScore,
                                                       int b, int i, bool sup) {
  float s = sup ? NEGF : selScore[(size_t)b * PRE + i];
  unsigned tiev = 0xFFFFFFFFu - (unsigned)(b * 8192 + i);
  return ((unsigned long long)forder(s) << 32) | (unsigned long long)tiev;
}

// ---------- kernel E: greedy scan + post-NMS compaction (fused, single wave) ----------
__global__ __launch_bounds__(64, 1) void k_scan(const float* __restrict__ boxes,
                                                const unsigned long long* __restrict__ mask,
                                                const float* __restrict__ selScore,
                                                unsigned long long* __restrict__ pk) {
  const int b = blockIdx.x, l = threadIdx.x;   // 64 lanes
  const unsigned long long* m = mask + (size_t)b * JMAX * PREP;

  __shared__ float4 s_box[PRE];                // fallback only (96 KB)
  __shared__ unsigned long long s_alive[MWORDS];

  for (int i = l; i < MWORDS; i += 64) s_alive[i] = 0ull;   // trailing words = dead

  unsigned long long colAlive = 0;             // bit k = alive(row 64k+l), k < JMAX
  int count = 0;
  bool loaded = false;
  int j = 0;

  for (; j < MWORDS; ++j) {
    unsigned long long word, diag;
    if (j < JMAX) {
      const unsigned long long* mcol = m + (size_t)j * PREP;
      unsigned long long acc = 0;
      int k = 0;
      for (; k + 8 <= j; k += 8) {             // 8 independent loads -> 1 vmcnt batch
        unsigned long long v0 = mcol[(k + 0) * 64 + l];
        unsigned long long v1 = mcol[(k + 1) * 64 + l];
        unsigned long long v2 = mcol[(k + 2) * 64 + l];
        unsigned long long v3 = mcol[(k + 3) * 64 + l];
        unsigned long long v4 = mcol[(k + 4) * 64 + l];
        unsigned long long v5 = mcol[(k + 5) * 64 + l];
        unsigned long long v6 = mcol[(k + 6) * 64 + l];
        unsigned long long v7 = mcol[(k + 7) * 64 + l];
        acc |= v0 & (0ull - ((colAlive >> (k + 0)) & 1ull));
        acc |= v1 & (0ull - ((colAlive >> (k + 1)) & 1ull));
        acc |= v2 & (0ull - ((colAlive >> (k + 2)) & 1ull));
        acc |= v3 & (0ull - ((colAlive >> (k + 3)) & 1ull));
        acc |= v4 & (0ull - ((colAlive >> (k + 4)) & 1ull));
        acc |= v5 & (0ull - ((colAlive >> (k + 5)) & 1ull));
        acc |= v6 & (0ull - ((colAlive >> (k + 6)) & 1ull));
        acc |= v7 & (0ull - ((colAlive >> (k + 7)) & 1ull));
      }
      for (; k < j; ++k)
        acc |= mcol[k * 64 + l] & (0ull - ((colAlive >> k) & 1ull));
      diag = mcol[j * 64 + l];
      #pragma unroll
      for (int off = 32; off > 0; off >>= 1) acc |= __shfl_xor(acc, off, 64);
      word = acc;
    } else {
      if (!loaded) {                           // wave-uniform lazy box load
        for (int r = l; r < PRE; r += 64)
          s_box[r] = ((const float4*)boxes)[(size_t)b * PRE + r];
        loaded = true;
      }
      int col = j * 64 + l;
      bool supp = false;
      if (col < PRE) {
        float4 c4 = s_box[col];
        float ca = area_of(c4.x, c4.y, c4.z, c4.w);
        for (int r = 0; r < j * 64; ++r) {
          if ((s_alive[r >> 6] >> (r & 63)) & 1ull) {
            float4 r4 = s_box[r];
            supp |= iou_gt(r4.x, r4.y, r4.z, r4.w,
                           area_of(r4.x, r4.y, r4.z, r4.w),
                           c4.x, c4.y, c4.z, c4.w, ca);
          }
        }
      }
      word = __ballot(supp);
      diag = 0ull;
      int row = j * 64 + l;
      int jn = min(64, PRE - j * 64);
      if (row < PRE) {
        float4 b4 = s_box[row];
        float ai = area_of(b4.x, b4.y, b4.z, b4.w);
        for (int jj = l + 1; jj < jn; ++jj) {
          float4 c4 = s_box[j * 64 + jj];
          if (iou_gt(b4.x, b4.y, b4.z, b4.w, ai,
                     c4.x, c4.y, c4.z, c4.w,
                     area_of(c4.x, c4.y, c4.z, c4.w)))
            diag |= (1ull << jj);
        }
      }
    }

    // SPARSE serial chain: visit only rows with nonzero diag, in order
    unsigned long long nz = __ballot(diag != 0ull);
    unsigned vdlo = (unsigned)diag, vdhi = (unsigned)(diag >> 32);
    unsigned slo = __builtin_amdgcn_readfirstlane((unsigned)word);
    unsigned shi = __builtin_amdgcn_readfirstlane((unsigned)(word >> 32));
    unsigned long long st = ((unsigned long long)shi << 32) | slo;
    while (nz) {
      int kk = (int)__builtin_ctzll(nz);
      nz &= nz - 1ull;
      if (!((st >> kk) & 1ull)) {
        unsigned dlo = __builtin_amdgcn_readlane(vdlo, kk);
        unsigned dhi = __builtin_amdgcn_readlane(vdhi, kk);
        st |= ((unsigned long long)dhi << 32) | dlo;
      }
    }
    unsigned long long vmask = (j < MWORDS - 1) ? ~0ull : ((1ull << 48) - 1ull);
    unsigned long long alive = (~st) & vmask;
    if (l == 0) s_alive[j] = alive;
    if (j < 64) colAlive |= ((alive >> l) & 1ull) << j;
    count += __popcll(alive);                  // uniform
    if (count >= POST) break;
  }

  // ---- fused post-NMS top-1000 compaction (s_alive-only; unprocessed = dead)
  const unsigned long long lastmask = (1ull << 48) - 1ull;
  int base = 0;
  for (int w = 0; w < MWORDS && base < POST; ++w) {
    unsigned long long alive = s_alive[w];     // 0 for unprocessed words
    int pos = base + __popcll(alive & ((1ull << l) - 1ull));
    if (((alive >> l) & 1ull) && pos < POST)
      pk[(size_t)b * POST + pos] = make_key(selScore, b, w * 64 + l, false);
    base += __popcll(alive);
  }
  if (base < POST) {                           // rare: fewer than 1000 survivors
    int fill = base;
    for (int w = 0; w < MWORDS && fill < POST; ++w) {
      unsigned long long dead = ~s_alive[w];
      if (w == MWORDS - 1) dead &= lastmask;
      int pos = fill + __popcll(dead & ((1ull << l) - 1ull));
      if (((dead >> l) & 1ull) && pos < POST)
        pk[(size_t)b * POST + pos] = make_key(selScore, b, w * 64 + l, true);
      fill += __popcll(dead);
    }
  }
}

// ---------- kernel G: global top-1000 of 4000 — 4 threads/slot, 16 blocks ----------
// All 4096 keys in LDS (32 KB). Thread = (slotLocal, q): ranks its slot
// against quarter q of the table (1024 keys), then 2-step shfl_xor sum over
// the 4 adjacent lanes gives the full rank; q==0 writes the output row.
__global__ __launch_bounds__(1024) void k_final(const unsigned long long* __restrict__ pk,
                                                const float* __restrict__ boxes,
                                                float* __restrict__ out) {
  const int sc = blockIdx.x;                   // 16 blocks x 256 slots
  const int slotLocal = threadIdx.x >> 2, q = threadIdx.x & 3;
  const int slot = sc * 256 + slotLocal;
  __shared__ __align__(16) unsigned long long tile[4096];
  #pragma unroll
  for (int c = 0; c < 4; ++c) {
    int ji = c * 1024 + threadIdx.x;
    tile[ji] = (ji < B_ * POST) ? pk[ji] : 0ull;
  }
  __syncthreads();
  unsigned long long my = tile[slot];          // slot < 4096; slots >= B_*POST hold 0
  int r = 0;
  const ulonglong2* t2 = (const ulonglong2*)(tile + q * 1024);
  #pragma unroll 8
  for (int t = 0; t < 512; ++t) { ulonglong2 v = t2[t]; r += (v.x > my) + (v.y > my); }
  r += __shfl_xor(r, 1, 64);
  r += __shfl_xor(r, 2, 64);
  if (q == 0 && slot < B_ * POST && r < POST) {
    unsigned v = 0xFFFFFFFFu - (unsigned)(my & 0xFFFFFFFFull);
    int b = v >> 13, pos = v & 8191;
    float s = funorder((unsigned)(my >> 32));
    const float* bx = boxes + ((size_t)b * PRE + pos) * 4;
    out[r * 5 + 0] = (float)b;
    out[r * 5 + 1] = bx[0];
    out[r * 5 + 2] = bx[1];
    out[r * 5 + 3] = bx[2];
    out[r * 5 + 4] = bx[3];
    out[5 * POST + r] = s;
  }
}

// ---------- workspace layout (bytes, all 16-aligned) ----------
static constexpr size_t OFF_SELS = 0;                                    // B*PRE f32
static constexpr size_t OFF_BOX  = OFF_SELS + (size_t)B_ * PRE * 4;      // B*PRE*4 f32
static constexpr size_t OFF_MASK = OFF_BOX  + (size_t)B_ * PRE * 16;     // B*JMAX*PREP u64
static constexpr size_t OFF_PK   = OFF_MASK + (size_t)B_ * JMAX * PREP * 8; // B*POST u64
static constexpr size_t OFF_HIST = OFF_PK   + (size_t)B_ * POST * 8;     // B*HGRP*NBINS i32
static constexpr size_t OFF_CNT  = OFF_HIST + (size_t)B_ * HGRP * NBINS * 4; // B*CNTSTRIDE i32
static constexpr size_t OFF_CUTM = OFF_CNT  + (size_t)B_ * CNTSTRIDE * 4;// B*2 i32 (pad 32)
static constexpr size_t OFF_CAND = OFF_CUTM + 32;                        // B*NCAND u64
static constexpr size_t OFF_RKP  = OFF_CAND + (size_t)B_ * NCAND * 8;    // B*8*NCAND i32

extern "C" void kernel_launch(void* const* d_in, const int* in_sizes, int n_in,
                              void* d_out, int out_size, void* d_ws, size_t ws_size,
                              hipStream_t stream) {
  Ptrs P;
  bool interleaved = (n_in >= 2) && (in_sizes[1] == 2 * in_sizes[0]);
  for (int l = 0; l < 5; ++l) {
    if (interleaved) { P.cls[l] = (const float*)d_in[2 * l]; P.bbox[l] = (const float*)d_in[2 * l + 1]; }
    else             { P.cls[l] = (const float*)d_in[l];     P.bbox[l] = (const float*)d_in[5 + l]; }
  }
  const float* im_info = (const float*)d_in[10];

  char* ws = (char*)d_ws;
  float*              selScore = (float*)(ws + OFF_SELS);
  float*              selBoxes = (float*)(ws + OFF_BOX);
  unsigned long long* maskBuf  = (unsigned long long*)(ws + OFF_MASK);
  unsigned long long* postKeys = (unsigned long long*)(ws + OFF_PK);
  int*                histBuf  = (int*)(ws + OFF_HIST);
  int*                cntBuf   = (int*)(ws + OFF_CNT);
  int*                cutMBuf  = (int*)(ws + OFF_CUTM);
  unsigned long long* candBuf  = (unsigned long long*)(ws + OFF_CAND);
  int*                rankP    = (int*)(ws + OFF_RKP);
  float*              out      = (float*)d_out;

  k_hist<<<dim3(HGRP, B_), 1024, 0, stream>>>(P, histBuf);
  k_cut<<<B_, NBINS, 0, stream>>>(histBuf, cutMBuf, cntBuf);
  k_compact<<<dim3((N1 + 255) / 256, B_), 256, 0, stream>>>(P, cutMBuf, cntBuf, candBuf);
  k_rankp<<<dim3(64, B_), 1024, 0, stream>>>(candBuf, cutMBuf, rankP);
  k_rankdec<<<dim3(NCAND / 256, B_), 256, 0, stream>>>(P, im_info, candBuf, rankP, cutMBuf, selScore, selBoxes);
  k_mask<<<dim3(JMAX, JMAX, B_), 64, 0, stream>>>(selBoxes, maskBuf);
  k_scan<<<B_, 64, 0, stream>>>(selBoxes, maskBuf, selScore, postKeys);
  k_final<<<16, 1024, 0, stream>>>(postKeys, selBoxes, out);
}

// Round 19
// 141.497 us; speedup vs baseline: 2.1912x; 1.2543x over previous
//
#include <hip/hip_runtime.h>
#include <stdint.h>
#include <math.h>

static constexpr int B_   = 4;
static constexpr int N1   = 255780;   // total anchors per image across 5 levels
static constexpr int PRE  = 6000;
static constexpr int PREP = 6016;     // padded rows (multiple of 64)
static constexpr int POST = 1000;
static constexpr int MWORDS = 94;     // ceil(6000/64)
static constexpr int JMAX = 40;       // precomputed mask columns (stop measured ~24)
static constexpr int NCAND = 8192;    // candidate capacity per image
static constexpr int NBINS = 512;     // histogram bins
static constexpr int HGRP = 64;       // histogram partial groups per image
static constexpr int CNTSTRIDE = 32;  // ints; 128B — one cache line per image
static constexpr int QSTRIDE = 1026;  // padded quarter stride (8208B: bank-skewed, 16B-aligned)
static constexpr float NEGF = -1000000000.0f;

__device__ __constant__ int c_OFF[6] = {0,192000,240000,252000,255000,255780};
__device__ __constant__ int c_H[5]   = {200,100,50,25,13};
__device__ __constant__ int c_W[5]   = {320,160,80,40,20};
__device__ __constant__ int c_S[5]   = {4,8,16,32,64};

struct Ptrs { const float* cls[5]; const float* bbox[5]; };

// ---------- helpers ----------
__device__ __forceinline__ unsigned forder(float f) {
  unsigned u = __float_as_uint(f);
  return (u & 0x80000000u) ? ~u : (u | 0x80000000u);
}
__device__ __forceinline__ float funorder(unsigned u) {
  u = (u & 0x80000000u) ? (u & 0x7FFFFFFFu) : ~u;
  return __uint_as_float(u);
}
__device__ __forceinline__ int bucket_of(float s) {
  int bk = (int)(s * (float)NBINS);
  return max(0, min(NBINS - 1, bk));
}

// Exact division-free IoU test:  rn(inter/uni) > 0.7f  ⟺  inter ≥ m·uni,
// m = 0.7f + 2^-25 (midpoint to the next float; 0.7f mantissa is odd so the
// tie rounds UP). m(25b)×uni(24b) ≤ 49 bits → double product exact. uni > 0.
__device__ __forceinline__ bool iou_gt(float x1, float y1, float x2, float y2, float ai,
                                       float bx1, float by1, float bx2, float by2, float aj) {
  float xx1 = fmaxf(x1, bx1), yy1 = fmaxf(y1, by1);
  float xx2 = fminf(x2, bx2), yy2 = fminf(y2, by2);
  float ww = fmaxf(__fadd_rn(__fsub_rn(xx2, xx1), 1.0f), 0.0f);
  float hh = fmaxf(__fadd_rn(__fsub_rn(yy2, yy1), 1.0f), 0.0f);
  float inter = __fmul_rn(ww, hh);
  float uni = __fsub_rn(__fadd_rn(ai, aj), inter);
  return (double)inter >= ((double)0.7f + 0x1p-25) * (double)uni;
}
__device__ __forceinline__ float area_of(float ax1, float ay1, float ax2, float ay2) {
  return __fmul_rn(__fadd_rn(__fsub_rn(ax2, ax1), 1.0f),
                   __fadd_rn(__fsub_rn(ay2, ay1), 1.0f));
}

// score gather (no decode needed: with MIN_SIZE=0 every box is provably valid)
__device__ __forceinline__ float score_of(const Ptrs& P, int b, int i) {
  int lvl = (i >= c_OFF[4]) ? 4 : (i >= c_OFF[3]) ? 3 : (i >= c_OFF[2]) ? 2 : (i >= c_OFF[1]) ? 1 : 0;
  int rem = i - c_OFF[lvl];
  int a = rem % 3;
  int pos = rem / 3;
  size_t hw = (size_t)c_H[lvl] * c_W[lvl];
  return P.cls[lvl][((size_t)b * 6 + 3 + a) * hw + (size_t)pos];
}

// base anchor (legacy +1 convention), double math == numpy float64, rint == np.round
__device__ __forceinline__ void anchor_for(int lvl, int a, float& ax1, float& ay1, float& ax2, float& ay2) {
  int st = c_S[lvl];
  double size = (double)st * (double)st;
  double c = 0.5 * (double)(st - 1);
  double r = (a == 0) ? 0.5 : (a == 1) ? 1.0 : 2.0;
  double ws = rint(sqrt(size / r));
  double hs = rint(ws * r);
  double w2 = ws * 8.0, h2 = hs * 8.0;
  ax1 = (float)(c - 0.5 * (w2 - 1.0));
  ay1 = (float)(c - 0.5 * (h2 - 1.0));
  ax2 = (float)(c + 0.5 * (w2 - 1.0));
  ay2 = (float)(c + 0.5 * (h2 - 1.0));
}

// decode one anchor exactly as the reference (per-op f32 rounding, no FMA)
__device__ __forceinline__ void decode_one(const Ptrs& P, int b, int gi, float wlim, float hlim,
                                           float& x1, float& y1, float& x2, float& y2) {
  int lvl = (gi >= c_OFF[4]) ? 4 : (gi >= c_OFF[3]) ? 3 : (gi >= c_OFF[2]) ? 2 : (gi >= c_OFF[1]) ? 1 : 0;
  int rem = gi - c_OFF[lvl];
  int a = rem % 3;
  int pos = rem / 3;
  int W = c_W[lvl];
  int h = pos / W, w = pos - h * W;
  size_t hw = (size_t)c_H[lvl] * W;
  const float* bb = P.bbox[lvl] + ((size_t)b * 12 + 4 * a) * hw + (size_t)h * W + w;
  float d0 = bb[0], d1 = bb[hw], d2 = bb[2 * hw], d3 = bb[3 * hw];

  float ax1, ay1, ax2, ay2;
  anchor_for(lvl, a, ax1, ay1, ax2, ay2);
  int st = c_S[lvl];
  float sx = (float)(w * st), sy = (float)(h * st);
  ax1 += sx; ax2 += sx; ay1 += sy; ay2 += sy;   // exact integers

  float aw  = __fadd_rn(__fsub_rn(ax2, ax1), 1.0f);
  float ah  = __fadd_rn(__fsub_rn(ay2, ay1), 1.0f);
  float acx = __fadd_rn(ax1, __fmul_rn(0.5f, __fsub_rn(aw, 1.0f)));
  float acy = __fadd_rn(ay1, __fmul_rn(0.5f, __fsub_rn(ah, 1.0f)));
  float ew  = (float)exp((double)d2);
  float eh  = (float)exp((double)d3);
  float pcx = __fadd_rn(__fmul_rn(d0, aw), acx);
  float pcy = __fadd_rn(__fmul_rn(d1, ah), acy);
  float pw  = __fmul_rn(ew, aw);
  float ph  = __fmul_rn(eh, ah);
  float hwf = __fmul_rn(0.5f, __fsub_rn(pw, 1.0f));
  float hhf = __fmul_rn(0.5f, __fsub_rn(ph, 1.0f));
  x1 = __fsub_rn(pcx, hwf);
  x2 = __fadd_rn(pcx, hwf);
  y1 = __fsub_rn(pcy, hhf);
  y2 = __fadd_rn(pcy, hhf);
  x1 = fminf(fmaxf(x1, 0.0f), wlim);
  x2 = fminf(fmaxf(x2, 0.0f), wlim);
  y1 = fminf(fmaxf(y1, 0.0f), hlim);
  y2 = fminf(fmaxf(y2, 0.0f), hlim);
}

// ---------- kernel A: per-group partial histograms (no init, no global atomics) ----------
__global__ __launch_bounds__(1024) void k_hist(Ptrs P, int* hist) {
  const int b = blockIdx.y, g = blockIdx.x;    // HGRP groups per image
  __shared__ int h[NBINS];
  for (int k = threadIdx.x; k < NBINS; k += 1024) h[k] = 0;
  __syncthreads();
  const int step = HGRP * 1024;
  for (int i = g * 1024 + threadIdx.x; i < N1; i += step)
    atomicAdd(&h[bucket_of(score_of(P, b, i))], 1);
  __syncthreads();
  for (int k = threadIdx.x; k < NBINS; k += 1024)
    hist[((size_t)b * HGRP + g) * NBINS + k] = h[k];
}

// ---------- kernel B1: cutoff bin per image (sum partials + suffix-sum); zeroes cnt ----------
__global__ __launch_bounds__(NBINS) void k_cut(const int* hist, int* cutM, int* cnt) {
  int b = blockIdx.x, t = threadIdx.x;
  __shared__ int ts[NBINS];
  int mine = 0;
  for (int g = 0; g < HGRP; ++g) mine += hist[((size_t)b * HGRP + g) * NBINS + t];
  ts[t] = mine;
  if (t == 0) cnt[b * CNTSTRIDE] = 0;          // zero compaction counter (pre-k_compact)
  __syncthreads();
  for (int off = 1; off < NBINS; off <<= 1) {
    int v = ts[t] + ((t + off < NBINS) ? ts[t + off] : 0);
    __syncthreads();
    ts[t] = v;
    __syncthreads();
  }
  int nxt = (t + 1 < NBINS) ? ts[t + 1] : 0;
  if (ts[t] >= PRE && nxt < PRE) { cutM[b * 2] = t; cutM[b * 2 + 1] = ts[t]; }
}

// ---------- kernel B2: compact candidate keys — block-aggregated atomics ----------
__global__ __launch_bounds__(256) void k_compact(Ptrs P, const int* __restrict__ cutM, int* cnt,
                                                 unsigned long long* __restrict__ cand) {
  const int i = blockIdx.x * blockDim.x + threadIdx.x;
  const int b = blockIdx.y;
  const int wid = threadIdx.x >> 6;
  __shared__ int wcnts[4], wbase[4];

  int cut = cutM[b * 2];
  bool isc = false;
  float s = 0.0f;
  if (i < N1) {
    s = score_of(P, b, i);
    isc = bucket_of(s) >= cut;
  }
  unsigned long long ball = __ballot(isc);
  if ((threadIdx.x & 63) == 0) wcnts[wid] = __popcll(ball);
  __syncthreads();
  if (threadIdx.x == 0) {
    int tot = wcnts[0] + wcnts[1] + wcnts[2] + wcnts[3];
    int base = tot ? atomicAdd(&cnt[b * CNTSTRIDE], tot) : 0;
    wbase[0] = base;
    wbase[1] = base + wcnts[0];
    wbase[2] = base + wcnts[0] + wcnts[1];
    wbase[3] = base + wcnts[0] + wcnts[1] + wcnts[2];
  }
  __syncthreads();
  if (isc) {
    unsigned long long lower = ball & ((1ull << (threadIdx.x & 63)) - 1ull);
    int p = wbase[wid] + __popcll(lower);
    if (p < NCAND)
      cand[(size_t)b * NCAND + p] = ((unsigned long long)forder(s) << 32) |
                                    (unsigned long long)(0xFFFFFFFFu - (unsigned)i);
  }
}

// ---------- kernel B3a: PARTIAL ranks, one tile pair per block (256 blocks) ----------
__global__ __launch_bounds__(1024) void k_rankp(const unsigned long long* __restrict__ cand,
                                                const int* __restrict__ cutM,
                                                int* __restrict__ rankP) {
  const int b = blockIdx.y;
  const int sc = blockIdx.x >> 3, jc = blockIdx.x & 7;
  const int M = min(cutM[b * 2 + 1], NCAND);
  if (sc * 1024 >= M || jc * 1024 >= M) return;
  __shared__ __align__(16) unsigned long long tile[1024];
  const unsigned long long* src = cand + (size_t)b * NCAND;
  int ji = jc * 1024 + threadIdx.x;
  tile[threadIdx.x] = (ji < M) ? src[ji] : 0ull;
  __syncthreads();
  const int slot = sc * 1024 + threadIdx.x;
  unsigned long long my = (slot < M) ? src[slot] : ~0ull;
  int r = 0;
  const ulonglong2* t2 = (const ulonglong2*)tile;
  #pragma unroll 8
  for (int t = 0; t < 512; ++t) { ulonglong2 v = t2[t]; r += (v.x > my) + (v.y > my); }
  rankP[((size_t)(b * 8 + jc)) * NCAND + slot] = r;
}

// ---------- kernel B3b+C fused: sum partials, scatter by rank, decode boxes ----------
__global__ void k_rankdec(Ptrs P, const float* im_info,
                          const unsigned long long* cand, const int* rankP,
                          const int* cutM, float* selScore, float* boxes) {
  int b = blockIdx.y, slot = blockIdx.x * 256 + threadIdx.x;
  const int M = min(cutM[b * 2 + 1], NCAND);
  if (slot >= M) return;                       // stale slots never read
  const int njc = (M + 1023) >> 10;
  int r = 0;
  for (int jc = 0; jc < njc; ++jc)
    r += rankP[((size_t)(b * 8 + jc)) * NCAND + slot];
  if (r < PRE) {
    unsigned long long my = cand[(size_t)b * NCAND + slot];
    int gi = (int)(0xFFFFFFFFu - (unsigned)(my & 0xFFFFFFFFull));
    selScore[(size_t)b * PRE + r] = funorder((unsigned)(my >> 32));
    float wlim = __fsub_rn(im_info[b * 3 + 1], 1.0f);
    float hlim = __fsub_rn(im_info[b * 3 + 0], 1.0f);
    float x1, y1, x2, y2;
    decode_one(P, b, gi, wlim, hlim, x1, y1, x2, y2);
    float* o = boxes + ((size_t)b * PRE + r) * 4;
    o[0] = x1; o[1] = y1; o[2] = x2; o[3] = y2;
  }
}

// ---------- kernel D: IoU bitmasks — columns cb<JMAX only, transposed [cb][row] ----------
__global__ void k_mask(const float* boxes, unsigned long long* mask) {
  int cb = blockIdx.x, rb = blockIdx.y, b = blockIdx.z;
  if (rb > cb) return;                      // lower triangle never read
  int t = threadIdx.x;  // 64 threads
  __shared__ float cx1[64], cy1[64], cx2[64], cy2[64], car[64];
  int j0 = cb * 64;
  int jn = min(64, PRE - j0);
  if (t < jn) {
    const float* bj = boxes + ((size_t)b * PRE + j0 + t) * 4;
    float a1 = bj[0], b1 = bj[1], a2 = bj[2], b2 = bj[3];
    cx1[t] = a1; cy1[t] = b1; cx2[t] = a2; cy2[t] = b2;
    car[t] = area_of(a1, b1, a2, b2);
  }
  __syncthreads();
  int i = rb * 64 + t;
  if (i >= PRE) return;
  const float* bi = boxes + ((size_t)b * PRE + i) * 4;
  float x1 = bi[0], y1 = bi[1], x2 = bi[2], y2 = bi[3];
  float ai = area_of(x1, y1, x2, y2);
  unsigned long long bits = 0;
  if (cb > rb) {
    for (int jj = 0; jj < jn; ++jj)
      if (iou_gt(x1, y1, x2, y2, ai, cx1[jj], cy1[jj], cx2[jj], cy2[jj], car[jj]))
        bits |= (1ull << jj);
  } else {                                  // diagonal block: j > i only
    for (int jj = t + 1; jj < jn; ++jj)
      if (iou_gt(x1, y1, x2, y2, ai, cx1[jj], cy1[jj], cx2[jj], cy2[jj], car[jj]))
        bits |= (1ull << jj);
  }
  mask[((size_t)b * JMAX + cb) * PREP + i] = bits;   // coalesced over i
}

// ---------- survivor/suppressed key ----------
__device__ __forceinline__ unsigned long long make_key(const float* selScore,
                                                       int b, int i, bool sup) {
  float s = sup ? NEGF : selScore[(size_t)b * PRE + i];
  unsigned tiev = 0xFFFFFFFFu - (unsigned)(b * 8192 + i);
  return ((unsigned long long)forder(s) << 32) | (unsigned long long)tiev;
}

// ---------- kernel E: greedy scan + post-NMS compaction (fused, single wave) ----------
__global__ __launch_bounds__(64, 1) void k_scan(const float* __restrict__ boxes,
                                                const unsigned long long* __restrict__ mask,
                                                const float* __restrict__ selScore,
                                                unsigned long long* __restrict__ pk) {
  const int b = blockIdx.x, l = threadIdx.x;   // 64 lanes
  const unsigned long long* m = mask + (size_t)b * JMAX * PREP;

  __shared__ float4 s_box[PRE];                // fallback only (96 KB)
  __shared__ unsigned long long s_alive[MWORDS];

  for (int i = l; i < MWORDS; i += 64) s_alive[i] = 0ull;   // trailing words = dead

  unsigned long long colAlive = 0;             // bit k = alive(row 64k+l), k < JMAX
  int count = 0;
  bool loaded = false;
  int j = 0;

  for (; j < MWORDS; ++j) {
    unsigned long long word, diag;
    if (j < JMAX) {
      const unsigned long long* mcol = m + (size_t)j * PREP;
      unsigned long long acc = 0;
      int k = 0;
      for (; k + 8 <= j; k += 8) {             // 8 independent loads -> 1 vmcnt batch
        unsigned long long v0 = mcol[(k + 0) * 64 + l];
        unsigned long long v1 = mcol[(k + 1) * 64 + l];
        unsigned long long v2 = mcol[(k + 2) * 64 + l];
        unsigned long long v3 = mcol[(k + 3) * 64 + l];
        unsigned long long v4 = mcol[(k + 4) * 64 + l];
        unsigned long long v5 = mcol[(k + 5) * 64 + l];
        unsigned long long v6 = mcol[(k + 6) * 64 + l];
        unsigned long long v7 = mcol[(k + 7) * 64 + l];
        acc |= v0 & (0ull - ((colAlive >> (k + 0)) & 1ull));
        acc |= v1 & (0ull - ((colAlive >> (k + 1)) & 1ull));
        acc |= v2 & (0ull - ((colAlive >> (k + 2)) & 1ull));
        acc |= v3 & (0ull - ((colAlive >> (k + 3)) & 1ull));
        acc |= v4 & (0ull - ((colAlive >> (k + 4)) & 1ull));
        acc |= v5 & (0ull - ((colAlive >> (k + 5)) & 1ull));
        acc |= v6 & (0ull - ((colAlive >> (k + 6)) & 1ull));
        acc |= v7 & (0ull - ((colAlive >> (k + 7)) & 1ull));
      }
      for (; k < j; ++k)
        acc |= mcol[k * 64 + l] & (0ull - ((colAlive >> k) & 1ull));
      diag = mcol[j * 64 + l];
      #pragma unroll
      for (int off = 32; off > 0; off >>= 1) acc |= __shfl_xor(acc, off, 64);
      word = acc;
    } else {
      if (!loaded) {                           // wave-uniform lazy box load
        for (int r = l; r < PRE; r += 64)
          s_box[r] = ((const float4*)boxes)[(size_t)b * PRE + r];
        loaded = true;
      }
      int col = j * 64 + l;
      bool supp = false;
      if (col < PRE) {
        float4 c4 = s_box[col];
        float ca = area_of(c4.x, c4.y, c4.z, c4.w);
        for (int r = 0; r < j * 64; ++r) {
          if ((s_alive[r >> 6] >> (r & 63)) & 1ull) {
            float4 r4 = s_box[r];
            supp |= iou_gt(r4.x, r4.y, r4.z, r4.w,
                           area_of(r4.x, r4.y, r4.z, r4.w),
                           c4.x, c4.y, c4.z, c4.w, ca);
          }
        }
      }
      word = __ballot(supp);
      diag = 0ull;
      int row = j * 64 + l;
      int jn = min(64, PRE - j * 64);
      if (row < PRE) {
        float4 b4 = s_box[row];
        float ai = area_of(b4.x, b4.y, b4.z, b4.w);
        for (int jj = l + 1; jj < jn; ++jj) {
          float4 c4 = s_box[j * 64 + jj];
          if (iou_gt(b4.x, b4.y, b4.z, b4.w, ai,
                     c4.x, c4.y, c4.z, c4.w,
                     area_of(c4.x, c4.y, c4.z, c4.w)))
            diag |= (1ull << jj);
        }
      }
    }

    // SPARSE serial chain: visit only rows with nonzero diag, in order
    unsigned long long nz = __ballot(diag != 0ull);
    unsigned vdlo = (unsigned)diag, vdhi = (unsigned)(diag >> 32);
    unsigned slo = __builtin_amdgcn_readfirstlane((unsigned)word);
    unsigned shi = __builtin_amdgcn_readfirstlane((unsigned)(word >> 32));
    unsigned long long st = ((unsigned long long)shi << 32) | slo;
    while (nz) {
      int kk = (int)__builtin_ctzll(nz);
      nz &= nz - 1ull;
      if (!((st >> kk) & 1ull)) {
        unsigned dlo = __builtin_amdgcn_readlane(vdlo, kk);
        unsigned dhi = __builtin_amdgcn_readlane(vdhi, kk);
        st |= ((unsigned long long)dhi << 32) | dlo;
      }
    }
    unsigned long long vmask = (j < MWORDS - 1) ? ~0ull : ((1ull << 48) - 1ull);
    unsigned long long alive = (~st) & vmask;
    if (l == 0) s_alive[j] = alive;
    if (j < 64) colAlive |= ((alive >> l) & 1ull) << j;
    count += __popcll(alive);                  // uniform
    if (count >= POST) break;
  }

  // ---- fused post-NMS top-1000 compaction (s_alive-only; unprocessed = dead)
  const unsigned long long lastmask = (1ull << 48) - 1ull;
  int base = 0;
  for (int w = 0; w < MWORDS && base < POST; ++w) {
    unsigned long long alive = s_alive[w];     // 0 for unprocessed words
    int pos = base + __popcll(alive & ((1ull << l) - 1ull));
    if (((alive >> l) & 1ull) && pos < POST)
      pk[(size_t)b * POST + pos] = make_key(selScore, b, w * 64 + l, false);
    base += __popcll(alive);
  }
  if (base < POST) {                           // rare: fewer than 1000 survivors
    int fill = base;
    for (int w = 0; w < MWORDS && fill < POST; ++w) {
      unsigned long long dead = ~s_alive[w];
      if (w == MWORDS - 1) dead &= lastmask;
      int pos = fill + __popcll(dead & ((1ull << l) - 1ull));
      if (((dead >> l) & 1ull) && pos < POST)
        pk[(size_t)b * POST + pos] = make_key(selScore, b, w * 64 + l, true);
      fill += __popcll(dead);
    }
  }
}

// ---------- kernel G: global top-1000 of 4000 — 4 threads/slot, bank-skewed quarters ----------
// Quarter stride = 1026 elements (8208B): 8208/4 = 2052 ≡ 4 (mod 32), so the
// four quarter bases land on banks 0/4/8/12 — the 4 lanes of one slot read
// DISTINCT banks (was: 8192B stride ≡ bank 0 for all → 4-way conflict, 1.57M
// conflict cycles in R18). 8208 is 16B-aligned so ulonglong2 reads stay legal.
// Pad slots (1024,1025 of each quarter) are never read.
__global__ __launch_bounds__(1024) void k_final(const unsigned long long* __restrict__ pk,
                                                const float* __restrict__ boxes,
                                                float* __restrict__ out) {
  const int sc = blockIdx.x;                   // 16 blocks x 256 slots
  const int slotLocal = threadIdx.x >> 2, q = threadIdx.x & 3;
  const int slot = sc * 256 + slotLocal;
  __shared__ __align__(16) unsigned long long tile[4 * QSTRIDE];
  #pragma unroll
  for (int c = 0; c < 4; ++c) {
    int ji = c * 1024 + threadIdx.x;
    tile[c * QSTRIDE + threadIdx.x] = (ji < B_ * POST) ? pk[ji] : 0ull;
  }
  __syncthreads();
  unsigned long long my = tile[(slot >> 10) * QSTRIDE + (slot & 1023)];
  int r = 0;
  const ulonglong2* t2 = (const ulonglong2*)(tile + q * QSTRIDE);
  #pragma unroll 8
  for (int t = 0; t < 512; ++t) { ulonglong2 v = t2[t]; r += (v.x > my) + (v.y > my); }
  r += __shfl_xor(r, 1, 64);
  r += __shfl_xor(r, 2, 64);
  if (q == 0 && slot < B_ * POST && r < POST) {
    unsigned v = 0xFFFFFFFFu - (unsigned)(my & 0xFFFFFFFFull);
    int b = v >> 13, pos = v & 8191;
    float s = funorder((unsigned)(my >> 32));
    const float* bx = boxes + ((size_t)b * PRE + pos) * 4;
    out[r * 5 + 0] = (float)b;
    out[r * 5 + 1] = bx[0];
    out[r * 5 + 2] = bx[1];
    out[r * 5 + 3] = bx[2];
    out[r * 5 + 4] = bx[3];
    out[5 * POST + r] = s;
  }
}

// ---------- workspace layout (bytes, all 16-aligned) ----------
static constexpr size_t OFF_SELS = 0;                                    // B*PRE f32
static constexpr size_t OFF_BOX  = OFF_SELS + (size_t)B_ * PRE * 4;      // B*PRE*4 f32
static constexpr size_t OFF_MASK = OFF_BOX  + (size_t)B_ * PRE * 16;     // B*JMAX*PREP u64
static constexpr size_t OFF_PK   = OFF_MASK + (size_t)B_ * JMAX * PREP * 8; // B*POST u64
static constexpr size_t OFF_HIST = OFF_PK   + (size_t)B_ * POST * 8;     // B*HGRP*NBINS i32
static constexpr size_t OFF_CNT  = OFF_HIST + (size_t)B_ * HGRP * NBINS * 4; // B*CNTSTRIDE i32
static constexpr size_t OFF_CUTM = OFF_CNT  + (size_t)B_ * CNTSTRIDE * 4;// B*2 i32 (pad 32)
static constexpr size_t OFF_CAND = OFF_CUTM + 32;                        // B*NCAND u64
static constexpr size_t OFF_RKP  = OFF_CAND + (size_t)B_ * NCAND * 8;    // B*8*NCAND i32

extern "C" void kernel_launch(void* const* d_in, const int* in_sizes, int n_in,
                              void* d_out, int out_size, void* d_ws, size_t ws_size,
                              hipStream_t stream) {
  Ptrs P;
  bool interleaved = (n_in >= 2) && (in_sizes[1] == 2 * in_sizes[0]);
  for (int l = 0; l < 5; ++l) {
    if (interleaved) { P.cls[l] = (const float*)d_in[2 * l]; P.bbox[l] = (const float*)d_in[2 * l + 1]; }
    else             { P.cls[l] = (const float*)d_in[l];     P.bbox[l] = (const float*)d_in[5 + l]; }
  }
  const float* im_info = (const float*)d_in[10];

  char* ws = (char*)d_ws;
  float*              selScore = (float*)(ws + OFF_SELS);
  float*              selBoxes = (float*)(ws + OFF_BOX);
  unsigned long long* maskBuf  = (unsigned long long*)(ws + OFF_MASK);
  unsigned long long* postKeys = (unsigned long long*)(ws + OFF_PK);
  int*                histBuf  = (int*)(ws + OFF_HIST);
  int*                cntBuf   = (int*)(ws + OFF_CNT);
  int*                cutMBuf  = (int*)(ws + OFF_CUTM);
  unsigned long long* candBuf  = (unsigned long long*)(ws + OFF_CAND);
  int*                rankP    = (int*)(ws + OFF_RKP);
  float*              out      = (float*)d_out;

  k_hist<<<dim3(HGRP, B_), 1024, 0, stream>>>(P, histBuf);
  k_cut<<<B_, NBINS, 0, stream>>>(histBuf, cutMBuf, cntBuf);
  k_compact<<<dim3((N1 + 255) / 256, B_), 256, 0, stream>>>(P, cutMBuf, cntBuf, candBuf);
  k_rankp<<<dim3(64, B_), 1024, 0, stream>>>(candBuf, cutMBuf, rankP);
  k_rankdec<<<dim3(NCAND / 256, B_), 256, 0, stream>>>(P, im_info, candBuf, rankP, cutMBuf, selScore, selBoxes);
  k_mask<<<dim3(JMAX, JMAX, B_), 64, 0, stream>>>(selBoxes, maskBuf);
  k_scan<<<B_, 64, 0, stream>>>(selBoxes, maskBuf, selScore, postKeys);
  k_final<<<16, 1024, 0, stream>>>(postKeys, selBoxes, out);
}